// Round 5
// baseline (949.406 us; speedup 1.0000x reference)
//
#include <hip/hip_runtime.h>
#include <math.h>

// UrbanModelV2: encoder MLPs -> 4x GCNConv (2 graphs) -> gated combine -> LN-MLP head.
// N=100000, CTX=128, TGT=32, H=64, FUS=96, E1=1.6M, E2=0.8M. fp32 in/out.
//
// R5: (1) 8 rows/wave in dense kernels (weight vloads amortized 8x; VALU-bound);
//     (2) gather payload in bf16 (halves L2/L3 gather traffic; fp32 accumulate);
//     (3) CSR build fused across both graphs (combined 2N scan, one fill).

#define LN_EPS 1e-5f

__device__ __forceinline__ float gelu_exact(float x) {
    return 0.5f * x * (1.0f + erff(x * 0.70710678118654752440f));
}

__device__ __forceinline__ float wave_sum64(float v) {
#pragma unroll
    for (int off = 32; off > 0; off >>= 1)
        v += __shfl_xor(v, off, 64);
    return v;
}

__device__ __forceinline__ int load_edge(const void* ei, int is32, long idx) {
    return is32 ? ((const int*)ei)[idx] : (int)((const long long*)ei)[idx];
}

__device__ __forceinline__ unsigned short f32_to_bf16(float f) {
    unsigned int x = __float_as_uint(f);
    x += 0x7fffu + ((x >> 16) & 1u);   // round-to-nearest-even (finite values)
    return (unsigned short)(x >> 16);
}
__device__ __forceinline__ float bf16_to_f32(unsigned short u) {
    return __uint_as_float((unsigned int)u << 16);
}

// ---------------- dtype detection ----------------
__global__ __launch_bounds__(256) void detect_kernel(const unsigned char* __restrict__ mask_bytes,
                                                     const int* __restrict__ ei_words,
                                                     int* __restrict__ flags) {
    __shared__ int f0, f1;
    if (threadIdx.x == 0) { f0 = 0; f1 = 0; }
    __syncthreads();
    int i = threadIdx.x;
    if ((i & 3) != 0 && mask_bytes[i] != 0) f0 = 1;   // nonzero off-word byte => uint8 mask
    if (i < 64 && ei_words[2 * i + 1] != 0) f1 = 1;   // nonzero high word => int32 edges
    __syncthreads();
    if (threadIdx.x == 0) { flags[0] = f0; flags[1] = f1; }
}

// ---------------- CSR build (both graphs fused; transit nodes offset by N) ----------------
__global__ __launch_bounds__(256) void degcount_kernel(
    const void* __restrict__ ei1, int e1, const void* __restrict__ ei2, int e2,
    int n, const int* __restrict__ flags, int* __restrict__ deg)  // deg[2N]
{
    int i = blockIdx.x * 256 + threadIdx.x;
    if (i >= e1 + e2) return;
    int is32 = flags[1];
    int d, off;
    if (i < e1) { d = load_edge(ei1, is32, (long)e1 + i); off = 0; }
    else        { int k = i - e1; d = load_edge(ei2, is32, (long)e2 + k); off = n; }
    atomicAdd(&deg[off + d], 1);
}

__global__ __launch_bounds__(256) void dinv_kernel(const int* __restrict__ deg,
                                                   float* __restrict__ dinv, int n2) {
    int i = blockIdx.x * 256 + threadIdx.x;
    if (i < n2) dinv[i] = rsqrtf((float)deg[i] + 1.0f);  // +1 self-loop
}

__global__ __launch_bounds__(256) void scan1_kernel(const int* __restrict__ deg, int n2,
                                                    int* __restrict__ bsum) {
    __shared__ int red[4];
    int i = blockIdx.x * 256 + threadIdx.x;
    int v = (i < n2) ? deg[i] : 0;
#pragma unroll
    for (int off = 32; off > 0; off >>= 1)
        v += __shfl_xor(v, off, 64);
    if ((threadIdx.x & 63) == 0) red[threadIdx.x >> 6] = v;
    __syncthreads();
    if (threadIdx.x == 0) bsum[blockIdx.x] = red[0] + red[1] + red[2] + red[3];
}

__global__ __launch_bounds__(1024) void scan2_kernel(int* __restrict__ bsum, int nb) {
    __shared__ int s[1024];
    int t = threadIdx.x;
    s[t] = (t < nb) ? bsum[t] : 0;
    __syncthreads();
    for (int off = 1; off < 1024; off <<= 1) {
        int v = (t >= off) ? s[t - off] : 0;
        __syncthreads();
        if (t >= off) s[t] += v;
        __syncthreads();
    }
    if (t < nb) bsum[t] = (t == 0) ? 0 : s[t - 1];
}

__global__ __launch_bounds__(256) void scan3_kernel(const int* __restrict__ deg, int n2,
                                                    const int* __restrict__ boff,
                                                    int* __restrict__ rowptr,
                                                    int* __restrict__ cursor) {
    __shared__ int s[256];
    int t = threadIdx.x;
    int i = blockIdx.x * 256 + t;
    int v = (i < n2) ? deg[i] : 0;
    s[t] = v;
    __syncthreads();
    for (int off = 1; off < 256; off <<= 1) {
        int u = (t >= off) ? s[t - off] : 0;
        __syncthreads();
        if (t >= off) s[t] += u;
        __syncthreads();
    }
    int base = boff[blockIdx.x];
    if (i < n2) {
        int excl = base + s[t] - v;
        rowptr[i] = excl;
        cursor[i] = excl;
        if (i == n2 - 1) rowptr[n2] = base + s[t];
    }
}

__global__ __launch_bounds__(256) void fill_kernel(
    const void* __restrict__ ei1, int e1, const void* __restrict__ ei2, int e2,
    int n, const int* __restrict__ flags, const float* __restrict__ dinv,
    int* __restrict__ cursor, int2* __restrict__ edges)
{
    int i = blockIdx.x * 256 + threadIdx.x;
    if (i >= e1 + e2) return;
    int is32 = flags[1];
    int s, d, off;
    if (i < e1) {
        s = load_edge(ei1, is32, i);
        d = load_edge(ei1, is32, (long)e1 + i);
        off = 0;
    } else {
        int k = i - e1;
        s = load_edge(ei2, is32, k);
        d = load_edge(ei2, is32, (long)e2 + k);
        off = n;
    }
    int pos = atomicAdd(&cursor[off + d], 1);
    edges[pos] = make_int2(s, __float_as_int(dinv[off + s]));
}

// ---------------- encoder -> fused [N,96], 8 rows/wave ----------------
__global__ __launch_bounds__(256) void encoder_kernel(
    const float* __restrict__ context, const float* __restrict__ target,
    const void* __restrict__ mask, const int* __restrict__ flags,
    const float* __restrict__ mask_token,
    const float* __restrict__ ce_W1, const float* __restrict__ ce_b1,
    const float* __restrict__ ce_g, const float* __restrict__ ce_beta,
    const float* __restrict__ ce_W2, const float* __restrict__ ce_b2,
    const float* __restrict__ te_W, const float* __restrict__ te_b,
    float* __restrict__ fused, int n)
{
    __shared__ float cbuf[32][64];
    __shared__ float tbuf[32][32];
    int w = threadIdx.x >> 6;
    int j = threadIdx.x & 63;
    int r0 = __builtin_amdgcn_readfirstlane(blockIdx.x * 32 + w * 8);
    if (r0 >= n) return;  // N % 32 == 0

    // layer 1 (128 -> 64): 8 rows share each weight vload
    float y[8];
    float b1 = ce_b1[j];
#pragma unroll
    for (int r = 0; r < 8; ++r) y[r] = b1;
    const float* xr = context + (long)r0 * 128;
#pragma unroll 8
    for (int k = 0; k < 128; ++k) {
        float wv = ce_W1[k * 64 + j];
#pragma unroll
        for (int r = 0; r < 8; ++r)
            y[r] = fmaf(xr[r * 128 + k], wv, y[r]);
    }

    // LayerNorm + GELU per row -> cbuf (wave-private LDS)
    float lng = ce_g[j], lnb = ce_beta[j];
#pragma unroll
    for (int r = 0; r < 8; ++r) {
        float mean = wave_sum64(y[r]) * (1.0f / 64.0f);
        float xc = y[r] - mean;
        float var = wave_sum64(xc * xc) * (1.0f / 64.0f);
        cbuf[w * 8 + r][j] = gelu_exact(xc * rsqrtf(var + LN_EPS) * lng + lnb);
    }

    // masked target: 8 rows x 32 dims over 64 lanes (2 rows per pass)
    int tr = j >> 5;
    int tj = j & 31;
#pragma unroll
    for (int rr = 0; rr < 4; ++rr) {
        int r = tr + rr * 2;
        long mi = (long)(r0 + r) * 32 + tj;
        int mraw = flags[0] ? (int)((const unsigned char*)mask)[mi]
                            : ((const int*)mask)[mi];
        float m = mraw ? 1.0f : 0.0f;
        tbuf[w * 8 + r][tj] = target[mi] * (1.0f - m) + mask_token[tj] * m;
    }

    // layer 2 (64 -> 64)
    float y2[8];
    float b2 = ce_b2[j];
#pragma unroll
    for (int r = 0; r < 8; ++r) y2[r] = b2;
#pragma unroll 8
    for (int k = 0; k < 64; ++k) {
        float wv = ce_W2[k * 64 + j];
#pragma unroll
        for (int r = 0; r < 8; ++r)
            y2[r] = fmaf(cbuf[w * 8 + r][k], wv, y2[r]);
    }
#pragma unroll
    for (int r = 0; r < 8; ++r)
        fused[(long)(r0 + r) * 96 + j] = gelu_exact(y2[r]);

    // target encoder (32 -> 32)
#pragma unroll
    for (int rr = 0; rr < 4; ++rr) {
        int r = tr + rr * 2;
        float y3 = te_b[tj];
#pragma unroll
        for (int k = 0; k < 32; ++k)
            y3 = fmaf(tbuf[w * 8 + r][k], te_W[k * 32 + tj], y3);
        fused[(long)(r0 + r) * 96 + 64 + tj] = gelu_exact(y3);
    }
}

// ---------------- dense matmul: y_bf16[N,64] = x[N,FIN] @ W[FIN,64], 8 rows/wave ----------------
template <int FIN>
__global__ __launch_bounds__(256) void matmul_kernel(const float* __restrict__ x,
                                                     const float* __restrict__ W,
                                                     unsigned short* __restrict__ y, int n) {
    int w = threadIdx.x >> 6;
    int j = threadIdx.x & 63;
    int r0 = __builtin_amdgcn_readfirstlane(blockIdx.x * 32 + w * 8);
    if (r0 >= n) return;
    const float* xr = x + (long)r0 * FIN;
    float acc[8] = {0, 0, 0, 0, 0, 0, 0, 0};
#pragma unroll 8
    for (int k = 0; k < FIN; ++k) {
        float wv = W[k * 64 + j];
#pragma unroll
        for (int r = 0; r < 8; ++r)
            acc[r] = fmaf(xr[r * FIN + k], wv, acc[r]);
    }
#pragma unroll
    for (int r = 0; r < 8; ++r)
        y[(long)(r0 + r) * 64 + j] = f32_to_bf16(acc[r]);
}

// ---------------- gather + fused finalize (wave/node, bf16 payload, 4x ILP) ----------------
// pre = dinv_d * (sum_edges bf16(lin[src])*dinv_s + dinv_d*bf16(lin[node])) + b
// mode 0: out = gelu(pre); mode 1: out = a*pre; mode 2: out += (1-a)*pre
__global__ __launch_bounds__(256) void gather_kernel(
    const int* __restrict__ rowptr, const int2* __restrict__ edges,
    const float* __restrict__ dinv, const unsigned short* __restrict__ lin,
    const float* __restrict__ b, const float* __restrict__ alpha_ptr, int mode,
    float* __restrict__ out, int n)
{
    int w = threadIdx.x >> 6;
    int j = threadIdx.x & 63;
    int node = __builtin_amdgcn_readfirstlane(blockIdx.x * 4 + w);
    if (node >= n) return;

    int beg = rowptr[node];
    int end = rowptr[node + 1];
    float acc = 0.0f;
    for (int base = beg; base < end; base += 64) {
        int cnt = end - base;
        if (cnt > 64) cnt = 64;
        int2 rec = (j < cnt) ? edges[base + j] : make_int2(0, 0);
        int sj = rec.x;
        float dsj = __int_as_float(rec.y);
        int t = 0;
        for (; t + 4 <= cnt; t += 4) {
            int s0 = __shfl(sj, t, 64),     s1 = __shfl(sj, t + 1, 64);
            int s2 = __shfl(sj, t + 2, 64), s3 = __shfl(sj, t + 3, 64);
            float d0 = __shfl(dsj, t, 64),     d1 = __shfl(dsj, t + 1, 64);
            float d2 = __shfl(dsj, t + 2, 64), d3 = __shfl(dsj, t + 3, 64);
            float v0 = bf16_to_f32(lin[(long)s0 * 64 + j]);
            float v1 = bf16_to_f32(lin[(long)s1 * 64 + j]);
            float v2 = bf16_to_f32(lin[(long)s2 * 64 + j]);
            float v3 = bf16_to_f32(lin[(long)s3 * 64 + j]);
            acc = fmaf(v0, d0, acc);
            acc = fmaf(v1, d1, acc);
            acc = fmaf(v2, d2, acc);
            acc = fmaf(v3, d3, acc);
        }
        for (; t < cnt; ++t) {
            int s = __shfl(sj, t, 64);
            float ds = __shfl(dsj, t, 64);
            acc = fmaf(bf16_to_f32(lin[(long)s * 64 + j]), ds, acc);
        }
    }
    float dd = dinv[node];
    float pre = dd * (acc + dd * bf16_to_f32(lin[(long)node * 64 + j])) + b[j];

    long oi = (long)node * 64 + j;
    if (mode == 0) {
        out[oi] = gelu_exact(pre);
    } else {
        float a = 1.0f / (1.0f + expf(-alpha_ptr[0]));
        if (mode == 1) out[oi] = a * pre;
        else           out[oi] += (1.0f - a) * pre;
    }
}

// ---------------- head, 8 rows/wave ----------------
__global__ __launch_bounds__(256) void head_kernel(
    const float* __restrict__ hacc, const float* __restrict__ fused,
    const float* __restrict__ h_W1, const float* __restrict__ h_b1,
    const float* __restrict__ h_g, const float* __restrict__ h_beta,
    const float* __restrict__ h_W2, const float* __restrict__ h_b2,
    float* __restrict__ out, int n)
{
    __shared__ float zbuf[32][160];
    __shared__ float z2[32][64];
    int w = threadIdx.x >> 6;
    int j = threadIdx.x & 63;
    int r0 = __builtin_amdgcn_readfirstlane(blockIdx.x * 32 + w * 8);
    if (r0 >= n) return;

#pragma unroll
    for (int r = 0; r < 8; ++r) {
        zbuf[w * 8 + r][j] = hacc[(long)(r0 + r) * 64 + j];
        zbuf[w * 8 + r][64 + j] = fused[(long)(r0 + r) * 96 + j];
        if (j < 32) zbuf[w * 8 + r][128 + j] = fused[(long)(r0 + r) * 96 + 64 + j];
    }

    float y[8];
    float b1 = h_b1[j];
#pragma unroll
    for (int r = 0; r < 8; ++r) y[r] = b1;
#pragma unroll 8
    for (int k = 0; k < 160; ++k) {
        float wv = h_W1[k * 64 + j];
#pragma unroll
        for (int r = 0; r < 8; ++r)
            y[r] = fmaf(zbuf[w * 8 + r][k], wv, y[r]);
    }

    float lng = h_g[j], lnb = h_beta[j];
#pragma unroll
    for (int r = 0; r < 8; ++r) {
        float mean = wave_sum64(y[r]) * (1.0f / 64.0f);
        float xc = y[r] - mean;
        float var = wave_sum64(xc * xc) * (1.0f / 64.0f);
        z2[w * 8 + r][j] = gelu_exact(xc * rsqrtf(var + LN_EPS) * lng + lnb);
    }

    int tr = j >> 5;
    int tj = j & 31;
#pragma unroll
    for (int rr = 0; rr < 4; ++rr) {
        int r = tr + rr * 2;
        float o = h_b2[tj];
#pragma unroll
        for (int k = 0; k < 64; ++k)
            o = fmaf(z2[w * 8 + r][k], h_W2[k * 32 + tj], o);
        out[(long)(r0 + r) * 32 + tj] = o;
    }
}

extern "C" void kernel_launch(void* const* d_in, const int* in_sizes, int n_in,
                              void* d_out, int out_size, void* d_ws, size_t ws_size,
                              hipStream_t stream) {
    const float* context    = (const float*)d_in[0];
    const float* target     = (const float*)d_in[1];
    const void*  mask       = d_in[2];
    const void*  adj_ei     = d_in[3];
    const void*  tr_ei      = d_in[4];
    const float* mask_token = (const float*)d_in[5];
    const float* ce_W1 = (const float*)d_in[6];
    const float* ce_b1 = (const float*)d_in[7];
    const float* ce_g  = (const float*)d_in[8];
    const float* ce_be = (const float*)d_in[9];
    const float* ce_W2 = (const float*)d_in[10];
    const float* ce_b2 = (const float*)d_in[11];
    const float* te_W  = (const float*)d_in[12];
    const float* te_b  = (const float*)d_in[13];
    const float* g1_W  = (const float*)d_in[14];
    const float* g1_b  = (const float*)d_in[15];
    const float* g2_W  = (const float*)d_in[16];
    const float* g2_b  = (const float*)d_in[17];
    const float* t1_W  = (const float*)d_in[18];
    const float* t1_b  = (const float*)d_in[19];
    const float* t2_W  = (const float*)d_in[20];
    const float* t2_b  = (const float*)d_in[21];
    const float* alpha = (const float*)d_in[22];
    const float* h_W1  = (const float*)d_in[23];
    const float* h_b1  = (const float*)d_in[24];
    const float* h_g   = (const float*)d_in[25];
    const float* h_be  = (const float*)d_in[26];
    const float* h_W2  = (const float*)d_in[27];
    const float* h_b2  = (const float*)d_in[28];

    const int N  = in_sizes[0] / 128;
    const int E1 = in_sizes[3] / 2;
    const int E2 = in_sizes[4] / 2;
    const int E  = E1 + E2;
    const int N2 = 2 * N;
    const int nb = (N2 + 255) / 256;  // 782 (scan2 handles <=1024)

    // ---- workspace layout ----
    char* p = (char*)d_ws;
    int*   flags  = (int*)p;              p += 64;
    float* fused  = (float*)p;            p += (size_t)N * 96 * 4;
    unsigned short* lin = (unsigned short*)p;  p += (size_t)N * 64 * 2;
    float* h1     = (float*)p;            p += (size_t)N * 64 * 4;
    float* hacc   = (float*)p;            p += (size_t)N * 64 * 4;
    float* dinv   = (float*)p;            p += (size_t)N2 * 4;      // [adj | transit]
    int*   deg    = (int*)p;              p += (size_t)N2 * 4;
    int*   rowptr = (int*)p;              p += (size_t)(N2 + 1) * 4;
    int*   cursor = (int*)p;              p += (size_t)N2 * 4;
    int*   bsum   = (int*)p;              p += 1024 * 4;
    int2*  edges  = (int2*)p;             p += (size_t)E * 8;       // [adj | transit]
    float* out    = (float*)d_out;

    const unsigned rowBlocks32 = (unsigned)((N + 31) / 32);
    const unsigned nodeBlocks  = (unsigned)((N + 3) / 4);
    const unsigned n2Blocks    = (unsigned)((N2 + 255) / 256);
    const unsigned eBlocks     = (unsigned)((E + 255) / 256);

    detect_kernel<<<1, 256, 0, stream>>>((const unsigned char*)mask, (const int*)adj_ei, flags);
    hipMemsetAsync(deg, 0, (size_t)N2 * sizeof(int), stream);

    // ---- CSR build (both graphs) ----
    degcount_kernel<<<eBlocks, 256, 0, stream>>>(adj_ei, E1, tr_ei, E2, N, flags, deg);
    dinv_kernel<<<n2Blocks, 256, 0, stream>>>(deg, dinv, N2);
    scan1_kernel<<<nb, 256, 0, stream>>>(deg, N2, bsum);
    scan2_kernel<<<1, 1024, 0, stream>>>(bsum, nb);
    scan3_kernel<<<nb, 256, 0, stream>>>(deg, N2, bsum, rowptr, cursor);
    fill_kernel<<<eBlocks, 256, 0, stream>>>(adj_ei, E1, tr_ei, E2, N, flags, dinv, cursor, edges);

    // ---- encoders -> fused ----
    encoder_kernel<<<rowBlocks32, 256, 0, stream>>>(context, target, mask, flags, mask_token,
                                                    ce_W1, ce_b1, ce_g, ce_be, ce_W2, ce_b2,
                                                    te_W, te_b, fused, N);

    const float* dinv_a = dinv;
    const float* dinv_t = dinv + N;
    const int*   row_a  = rowptr;
    const int*   row_t  = rowptr + N;

    // ---- spatial branch ----
    matmul_kernel<96><<<rowBlocks32, 256, 0, stream>>>(fused, g1_W, lin, N);
    gather_kernel<<<nodeBlocks, 256, 0, stream>>>(row_a, edges, dinv_a, lin, g1_b, alpha, 0, h1, N);
    matmul_kernel<64><<<rowBlocks32, 256, 0, stream>>>(h1, g2_W, lin, N);
    gather_kernel<<<nodeBlocks, 256, 0, stream>>>(row_a, edges, dinv_a, lin, g2_b, alpha, 1, hacc, N);

    // ---- transit branch ----
    matmul_kernel<96><<<rowBlocks32, 256, 0, stream>>>(fused, t1_W, lin, N);
    gather_kernel<<<nodeBlocks, 256, 0, stream>>>(row_t, edges, dinv_t, lin, t1_b, alpha, 0, h1, N);
    matmul_kernel<64><<<rowBlocks32, 256, 0, stream>>>(h1, t2_W, lin, N);
    gather_kernel<<<nodeBlocks, 256, 0, stream>>>(row_t, edges, dinv_t, lin, t2_b, alpha, 2, hacc, N);

    // ---- head ----
    head_kernel<<<rowBlocks32, 256, 0, stream>>>(hacc, fused, h_W1, h_b1, h_g, h_be,
                                                 h_W2, h_b2, out, N);
}

// Round 6
// 823.668 us; speedup vs baseline: 1.1527x; 1.1527x over previous
//
#include <hip/hip_runtime.h>
#include <math.h>

// UrbanModelV2: encoder MLPs -> 4x GCNConv (2 graphs) -> gated combine -> LN-MLP head.
// N=100000, CTX=128, TGT=32, H=64, FUS=96, E1=1.6M, E2=0.8M. fp32 in/out.
//
// R6: (1) the 4 GCN matmuls -> MFMA (mfma_f32_16x16x32_bf16), activations bf16
//     end-to-end (fused/lin/h1 stored bf16; hacc stays fp32 for the head).
//     (2) head regression fixed: 4 rows/wave, stage-1 inputs via wave-uniform
//     scalar loads (no 28KB LDS zbuf; LDS only for 4KB z2).

#define LN_EPS 1e-5f

typedef __attribute__((ext_vector_type(8))) short short8;    // 8 bf16 = 4 VGPRs
typedef __attribute__((ext_vector_type(4))) float float4v;   // MFMA acc

__device__ __forceinline__ float gelu_exact(float x) {
    return 0.5f * x * (1.0f + erff(x * 0.70710678118654752440f));
}

__device__ __forceinline__ float wave_sum64(float v) {
#pragma unroll
    for (int off = 32; off > 0; off >>= 1)
        v += __shfl_xor(v, off, 64);
    return v;
}

__device__ __forceinline__ int load_edge(const void* ei, int is32, long idx) {
    return is32 ? ((const int*)ei)[idx] : (int)((const long long*)ei)[idx];
}

__device__ __forceinline__ unsigned short f32_to_bf16(float f) {
    unsigned int x = __float_as_uint(f);
    x += 0x7fffu + ((x >> 16) & 1u);   // RNE, finite values
    return (unsigned short)(x >> 16);
}
__device__ __forceinline__ float bf16_to_f32(unsigned short u) {
    return __uint_as_float((unsigned int)u << 16);
}

// ---------------- dtype detection ----------------
__global__ __launch_bounds__(256) void detect_kernel(const unsigned char* __restrict__ mask_bytes,
                                                     const int* __restrict__ ei_words,
                                                     int* __restrict__ flags) {
    __shared__ int f0, f1;
    if (threadIdx.x == 0) { f0 = 0; f1 = 0; }
    __syncthreads();
    int i = threadIdx.x;
    if ((i & 3) != 0 && mask_bytes[i] != 0) f0 = 1;
    if (i < 64 && ei_words[2 * i + 1] != 0) f1 = 1;
    __syncthreads();
    if (threadIdx.x == 0) { flags[0] = f0; flags[1] = f1; }
}

// ---------------- CSR build (both graphs; transit offset by N) ----------------
__global__ __launch_bounds__(256) void degcount_kernel(
    const void* __restrict__ ei1, int e1, const void* __restrict__ ei2, int e2,
    int n, const int* __restrict__ flags, int* __restrict__ deg)
{
    int i = blockIdx.x * 256 + threadIdx.x;
    if (i >= e1 + e2) return;
    int is32 = flags[1];
    int d, off;
    if (i < e1) { d = load_edge(ei1, is32, (long)e1 + i); off = 0; }
    else        { int k = i - e1; d = load_edge(ei2, is32, (long)e2 + k); off = n; }
    atomicAdd(&deg[off + d], 1);
}

__global__ __launch_bounds__(256) void dinv_kernel(const int* __restrict__ deg,
                                                   float* __restrict__ dinv, int n2) {
    int i = blockIdx.x * 256 + threadIdx.x;
    if (i < n2) dinv[i] = rsqrtf((float)deg[i] + 1.0f);
}

__global__ __launch_bounds__(256) void scan1_kernel(const int* __restrict__ deg, int n2,
                                                    int* __restrict__ bsum) {
    __shared__ int red[4];
    int i = blockIdx.x * 256 + threadIdx.x;
    int v = (i < n2) ? deg[i] : 0;
#pragma unroll
    for (int off = 32; off > 0; off >>= 1)
        v += __shfl_xor(v, off, 64);
    if ((threadIdx.x & 63) == 0) red[threadIdx.x >> 6] = v;
    __syncthreads();
    if (threadIdx.x == 0) bsum[blockIdx.x] = red[0] + red[1] + red[2] + red[3];
}

__global__ __launch_bounds__(1024) void scan2_kernel(int* __restrict__ bsum, int nb) {
    __shared__ int s[1024];
    int t = threadIdx.x;
    s[t] = (t < nb) ? bsum[t] : 0;
    __syncthreads();
    for (int off = 1; off < 1024; off <<= 1) {
        int v = (t >= off) ? s[t - off] : 0;
        __syncthreads();
        if (t >= off) s[t] += v;
        __syncthreads();
    }
    if (t < nb) bsum[t] = (t == 0) ? 0 : s[t - 1];
}

__global__ __launch_bounds__(256) void scan3_kernel(const int* __restrict__ deg, int n2,
                                                    const int* __restrict__ boff,
                                                    int* __restrict__ rowptr,
                                                    int* __restrict__ cursor) {
    __shared__ int s[256];
    int t = threadIdx.x;
    int i = blockIdx.x * 256 + t;
    int v = (i < n2) ? deg[i] : 0;
    s[t] = v;
    __syncthreads();
    for (int off = 1; off < 256; off <<= 1) {
        int u = (t >= off) ? s[t - off] : 0;
        __syncthreads();
        if (t >= off) s[t] += u;
        __syncthreads();
    }
    int base = boff[blockIdx.x];
    if (i < n2) {
        int excl = base + s[t] - v;
        rowptr[i] = excl;
        cursor[i] = excl;
        if (i == n2 - 1) rowptr[n2] = base + s[t];
    }
}

__global__ __launch_bounds__(256) void fill_kernel(
    const void* __restrict__ ei1, int e1, const void* __restrict__ ei2, int e2,
    int n, const int* __restrict__ flags, const float* __restrict__ dinv,
    int* __restrict__ cursor, int2* __restrict__ edges)
{
    int i = blockIdx.x * 256 + threadIdx.x;
    if (i >= e1 + e2) return;
    int is32 = flags[1];
    int s, d, off;
    if (i < e1) {
        s = load_edge(ei1, is32, i);
        d = load_edge(ei1, is32, (long)e1 + i);
        off = 0;
    } else {
        int k = i - e1;
        s = load_edge(ei2, is32, k);
        d = load_edge(ei2, is32, (long)e2 + k);
        off = n;
    }
    int pos = atomicAdd(&cursor[off + d], 1);
    edges[pos] = make_int2(s, __float_as_int(dinv[off + s]));
}

// ---------------- encoder -> fused bf16 [N,96], 8 rows/wave ----------------
__global__ __launch_bounds__(256) void encoder_kernel(
    const float* __restrict__ context, const float* __restrict__ target,
    const void* __restrict__ mask, const int* __restrict__ flags,
    const float* __restrict__ mask_token,
    const float* __restrict__ ce_W1, const float* __restrict__ ce_b1,
    const float* __restrict__ ce_g, const float* __restrict__ ce_beta,
    const float* __restrict__ ce_W2, const float* __restrict__ ce_b2,
    const float* __restrict__ te_W, const float* __restrict__ te_b,
    unsigned short* __restrict__ fused, int n)
{
    __shared__ float cbuf[32][64];
    __shared__ float tbuf[32][32];
    int w = threadIdx.x >> 6;
    int j = threadIdx.x & 63;
    int r0 = __builtin_amdgcn_readfirstlane(blockIdx.x * 32 + w * 8);
    if (r0 >= n) return;  // N % 32 == 0

    float y[8];
    float b1 = ce_b1[j];
#pragma unroll
    for (int r = 0; r < 8; ++r) y[r] = b1;
    const float* xr = context + (long)r0 * 128;
#pragma unroll 8
    for (int k = 0; k < 128; ++k) {
        float wv = ce_W1[k * 64 + j];
#pragma unroll
        for (int r = 0; r < 8; ++r)
            y[r] = fmaf(xr[r * 128 + k], wv, y[r]);
    }

    float lng = ce_g[j], lnb = ce_beta[j];
#pragma unroll
    for (int r = 0; r < 8; ++r) {
        float mean = wave_sum64(y[r]) * (1.0f / 64.0f);
        float xc = y[r] - mean;
        float var = wave_sum64(xc * xc) * (1.0f / 64.0f);
        cbuf[w * 8 + r][j] = gelu_exact(xc * rsqrtf(var + LN_EPS) * lng + lnb);
    }

    int tr = j >> 5;
    int tj = j & 31;
#pragma unroll
    for (int rr = 0; rr < 4; ++rr) {
        int r = tr + rr * 2;
        long mi = (long)(r0 + r) * 32 + tj;
        int mraw = flags[0] ? (int)((const unsigned char*)mask)[mi]
                            : ((const int*)mask)[mi];
        float m = mraw ? 1.0f : 0.0f;
        tbuf[w * 8 + r][tj] = target[mi] * (1.0f - m) + mask_token[tj] * m;
    }

    float y2[8];
    float b2 = ce_b2[j];
#pragma unroll
    for (int r = 0; r < 8; ++r) y2[r] = b2;
#pragma unroll 8
    for (int k = 0; k < 64; ++k) {
        float wv = ce_W2[k * 64 + j];
#pragma unroll
        for (int r = 0; r < 8; ++r)
            y2[r] = fmaf(cbuf[w * 8 + r][k], wv, y2[r]);
    }
#pragma unroll
    for (int r = 0; r < 8; ++r)
        fused[(long)(r0 + r) * 96 + j] = f32_to_bf16(gelu_exact(y2[r]));

#pragma unroll
    for (int rr = 0; rr < 4; ++rr) {
        int r = tr + rr * 2;
        float y3 = te_b[tj];
#pragma unroll
        for (int k = 0; k < 32; ++k)
            y3 = fmaf(tbuf[w * 8 + r][k], te_W[k * 32 + tj], y3);
        fused[(long)(r0 + r) * 96 + 64 + tj] = f32_to_bf16(gelu_exact(y3));
    }
}

// ---------------- MFMA matmul: y_bf16[N,64] = x_bf16[N,K] @ Wfp32[K,64] ----------------
// Wave computes 16x64 tiles (4 n-tiles of 16x16x32 MFMA). W converted/transposed
// once into LDS (row stride K+8 bf16 = 16*odd bytes: 16B-aligned b128 reads,
// 2-way bank alias = free), then B-frags held in registers across a grid-strided
// row loop. A-frag: lane(m=lane&15,q=lane>>4) loads 16B of row m at k=q*8.
// C/D: col=lane&15, row=q*4+reg.
template <int K>
__global__ __launch_bounds__(256) void mfma_matmul(const unsigned short* __restrict__ x,
                                                   const float* __restrict__ W,
                                                   unsigned short* __restrict__ y, int n) {
    constexpr int KS = K / 32;          // k-steps
    constexpr int STRIDE = K + 8;       // bf16 elems per LDS row
    __shared__ __align__(16) unsigned short wt[64 * STRIDE];

    // stage W -> LDS (bf16, transposed): thread (n0 = tid&63, kk = tid>>6)
    int n0 = threadIdx.x & 63;
    int kk = threadIdx.x >> 6;
    for (int k = kk; k < K; k += 4)
        wt[n0 * STRIDE + k] = f32_to_bf16(W[k * 64 + n0]);
    __syncthreads();

    int w = threadIdx.x >> 6;
    int lane = threadIdx.x & 63;
    int c = lane & 15;
    int q = lane >> 4;

    // B-frags into registers (shared by all row tiles)
    short8 bfrag[KS][4];
#pragma unroll
    for (int s = 0; s < KS; ++s)
#pragma unroll
        for (int nt = 0; nt < 4; ++nt)
            bfrag[s][nt] = *(const short8*)&wt[(nt * 16 + c) * STRIDE + s * 32 + q * 8];

    int T = n >> 4;  // row tiles (N%16==0)
    int stride = gridDim.x * 4;
    for (int t = __builtin_amdgcn_readfirstlane(blockIdx.x * 4 + w); t < T; t += stride) {
        int r0 = t << 4;
        const unsigned short* xa = x + (size_t)(r0 + c) * K + q * 8;  // m = c
        float4v acc[4] = {{0,0,0,0},{0,0,0,0},{0,0,0,0},{0,0,0,0}};
#pragma unroll
        for (int s = 0; s < KS; ++s) {
            short8 a = *(const short8*)(xa + s * 32);
#pragma unroll
            for (int nt = 0; nt < 4; ++nt)
                acc[nt] = __builtin_amdgcn_mfma_f32_16x16x32_bf16(a, bfrag[s][nt], acc[nt], 0, 0, 0);
        }
#pragma unroll
        for (int nt = 0; nt < 4; ++nt)
#pragma unroll
            for (int reg = 0; reg < 4; ++reg)
                y[(size_t)(r0 + q * 4 + reg) * 64 + nt * 16 + c] = f32_to_bf16(acc[nt][reg]);
    }
}

// ---------------- gather + fused finalize (wave/node, bf16 payload) ----------------
// pre = dinv_d * (sum_edges lin[src]*dinv_s + dinv_d*lin[node]) + b
// mode 0: outb = bf16(gelu(pre)); mode 1: outf = a*pre; mode 2: outf += (1-a)*pre
__global__ __launch_bounds__(256) void gather_kernel(
    const int* __restrict__ rowptr, const int2* __restrict__ edges,
    const float* __restrict__ dinv, const unsigned short* __restrict__ lin,
    const float* __restrict__ b, const float* __restrict__ alpha_ptr, int mode,
    unsigned short* __restrict__ outb, float* __restrict__ outf, int n)
{
    int w = threadIdx.x >> 6;
    int j = threadIdx.x & 63;
    int node = __builtin_amdgcn_readfirstlane(blockIdx.x * 4 + w);
    if (node >= n) return;

    int beg = rowptr[node];
    int end = rowptr[node + 1];
    float acc = 0.0f;
    for (int base = beg; base < end; base += 64) {
        int cnt = end - base;
        if (cnt > 64) cnt = 64;
        int2 rec = (j < cnt) ? edges[base + j] : make_int2(0, 0);
        int sj = rec.x;
        float dsj = __int_as_float(rec.y);
        int t = 0;
        for (; t + 4 <= cnt; t += 4) {
            int s0 = __shfl(sj, t, 64),     s1 = __shfl(sj, t + 1, 64);
            int s2 = __shfl(sj, t + 2, 64), s3 = __shfl(sj, t + 3, 64);
            float d0 = __shfl(dsj, t, 64),     d1 = __shfl(dsj, t + 1, 64);
            float d2 = __shfl(dsj, t + 2, 64), d3 = __shfl(dsj, t + 3, 64);
            float v0 = bf16_to_f32(lin[(long)s0 * 64 + j]);
            float v1 = bf16_to_f32(lin[(long)s1 * 64 + j]);
            float v2 = bf16_to_f32(lin[(long)s2 * 64 + j]);
            float v3 = bf16_to_f32(lin[(long)s3 * 64 + j]);
            acc = fmaf(v0, d0, acc);
            acc = fmaf(v1, d1, acc);
            acc = fmaf(v2, d2, acc);
            acc = fmaf(v3, d3, acc);
        }
        for (; t < cnt; ++t) {
            int s = __shfl(sj, t, 64);
            float ds = __shfl(dsj, t, 64);
            acc = fmaf(bf16_to_f32(lin[(long)s * 64 + j]), ds, acc);
        }
    }
    float dd = dinv[node];
    float pre = dd * (acc + dd * bf16_to_f32(lin[(long)node * 64 + j])) + b[j];

    long oi = (long)node * 64 + j;
    if (mode == 0) {
        outb[oi] = f32_to_bf16(gelu_exact(pre));
    } else {
        float a = 1.0f / (1.0f + expf(-alpha_ptr[0]));
        if (mode == 1) outf[oi] = a * pre;
        else           outf[oi] += (1.0f - a) * pre;
    }
}

// ---------------- head: 4 rows/wave, stage-1 via wave-uniform scalar loads ----------------
__global__ __launch_bounds__(256) void head_kernel(
    const float* __restrict__ hacc, const unsigned short* __restrict__ fused,
    const float* __restrict__ h_W1, const float* __restrict__ h_b1,
    const float* __restrict__ h_g, const float* __restrict__ h_beta,
    const float* __restrict__ h_W2, const float* __restrict__ h_b2,
    float* __restrict__ out, int n)
{
    __shared__ float z2[16][64];
    int w = threadIdx.x >> 6;
    int j = threadIdx.x & 63;
    int r0 = __builtin_amdgcn_readfirstlane(blockIdx.x * 16 + w * 4);
    if (r0 >= n) return;  // N % 16 == 0

    const float* hr = hacc + (size_t)r0 * 64;
    const unsigned short* fr = fused + (size_t)r0 * 96;

    float y[4];
    float b1 = h_b1[j];
#pragma unroll
    for (int r = 0; r < 4; ++r) y[r] = b1;
#pragma unroll 8
    for (int k = 0; k < 64; ++k) {
        float wv = h_W1[k * 64 + j];
#pragma unroll
        for (int r = 0; r < 4; ++r)
            y[r] = fmaf(hr[r * 64 + k], wv, y[r]);
    }
#pragma unroll 8
    for (int k = 0; k < 96; ++k) {
        float wv = h_W1[(64 + k) * 64 + j];
#pragma unroll
        for (int r = 0; r < 4; ++r)
            y[r] = fmaf(bf16_to_f32(fr[r * 96 + k]), wv, y[r]);
    }

    float lng = h_g[j], lnb = h_beta[j];
#pragma unroll
    for (int r = 0; r < 4; ++r) {
        float mean = wave_sum64(y[r]) * (1.0f / 64.0f);
        float xc = y[r] - mean;
        float var = wave_sum64(xc * xc) * (1.0f / 64.0f);
        z2[w * 4 + r][j] = gelu_exact(xc * rsqrtf(var + LN_EPS) * lng + lnb);
    }

    int tr = j >> 5;
    int tj = j & 31;
#pragma unroll
    for (int rr = 0; rr < 2; ++rr) {
        int r = tr + rr * 2;
        float o = h_b2[tj];
#pragma unroll
        for (int k = 0; k < 64; ++k)
            o = fmaf(z2[w * 4 + r][k], h_W2[k * 32 + tj], o);
        out[(long)(r0 + r) * 32 + tj] = o;
    }
}

extern "C" void kernel_launch(void* const* d_in, const int* in_sizes, int n_in,
                              void* d_out, int out_size, void* d_ws, size_t ws_size,
                              hipStream_t stream) {
    const float* context    = (const float*)d_in[0];
    const float* target     = (const float*)d_in[1];
    const void*  mask       = d_in[2];
    const void*  adj_ei     = d_in[3];
    const void*  tr_ei      = d_in[4];
    const float* mask_token = (const float*)d_in[5];
    const float* ce_W1 = (const float*)d_in[6];
    const float* ce_b1 = (const float*)d_in[7];
    const float* ce_g  = (const float*)d_in[8];
    const float* ce_be = (const float*)d_in[9];
    const float* ce_W2 = (const float*)d_in[10];
    const float* ce_b2 = (const float*)d_in[11];
    const float* te_W  = (const float*)d_in[12];
    const float* te_b  = (const float*)d_in[13];
    const float* g1_W  = (const float*)d_in[14];
    const float* g1_b  = (const float*)d_in[15];
    const float* g2_W  = (const float*)d_in[16];
    const float* g2_b  = (const float*)d_in[17];
    const float* t1_W  = (const float*)d_in[18];
    const float* t1_b  = (const float*)d_in[19];
    const float* t2_W  = (const float*)d_in[20];
    const float* t2_b  = (const float*)d_in[21];
    const float* alpha = (const float*)d_in[22];
    const float* h_W1  = (const float*)d_in[23];
    const float* h_b1  = (const float*)d_in[24];
    const float* h_g   = (const float*)d_in[25];
    const float* h_be  = (const float*)d_in[26];
    const float* h_W2  = (const float*)d_in[27];
    const float* h_b2  = (const float*)d_in[28];

    const int N  = in_sizes[0] / 128;
    const int E1 = in_sizes[3] / 2;
    const int E2 = in_sizes[4] / 2;
    const int E  = E1 + E2;
    const int N2 = 2 * N;
    const int nb = (N2 + 255) / 256;

    // ---- workspace layout (all regions 256B-aligned) ----
    char* p = (char*)d_ws;
    int*   flags  = (int*)p;                   p += 256;
    unsigned short* fused = (unsigned short*)p; p += (size_t)N * 96 * 2;
    unsigned short* lin   = (unsigned short*)p; p += (size_t)N * 64 * 2;
    unsigned short* h1    = (unsigned short*)p; p += (size_t)N * 64 * 2;
    float* hacc   = (float*)p;                 p += (size_t)N * 64 * 4;
    float* dinv   = (float*)p;                 p += (size_t)N2 * 4;
    int*   deg    = (int*)p;                   p += (size_t)N2 * 4;
    int*   rowptr = (int*)p;                   p += (size_t)(N2 + 64) * 4;
    int*   cursor = (int*)p;                   p += (size_t)N2 * 4;
    int*   bsum   = (int*)p;                   p += 1024 * 4;
    int2*  edges  = (int2*)p;                  p += (size_t)E * 8;
    float* out    = (float*)d_out;

    const unsigned rowBlocks32 = (unsigned)((N + 31) / 32);
    const unsigned headBlocks  = (unsigned)((N + 15) / 16);
    const unsigned nodeBlocks  = (unsigned)((N + 3) / 4);
    const unsigned n2Blocks    = (unsigned)((N2 + 255) / 256);
    const unsigned eBlocks     = (unsigned)((E + 255) / 256);
    const unsigned mmBlocks    = 391;

    detect_kernel<<<1, 256, 0, stream>>>((const unsigned char*)mask, (const int*)adj_ei, flags);
    hipMemsetAsync(deg, 0, (size_t)N2 * sizeof(int), stream);

    // ---- CSR build (both graphs) ----
    degcount_kernel<<<eBlocks, 256, 0, stream>>>(adj_ei, E1, tr_ei, E2, N, flags, deg);
    dinv_kernel<<<n2Blocks, 256, 0, stream>>>(deg, dinv, N2);
    scan1_kernel<<<nb, 256, 0, stream>>>(deg, N2, bsum);
    scan2_kernel<<<1, 1024, 0, stream>>>(bsum, nb);
    scan3_kernel<<<nb, 256, 0, stream>>>(deg, N2, bsum, rowptr, cursor);
    fill_kernel<<<eBlocks, 256, 0, stream>>>(adj_ei, E1, tr_ei, E2, N, flags, dinv, cursor, edges);

    // ---- encoders -> fused (bf16) ----
    encoder_kernel<<<rowBlocks32, 256, 0, stream>>>(context, target, mask, flags, mask_token,
                                                    ce_W1, ce_b1, ce_g, ce_be, ce_W2, ce_b2,
                                                    te_W, te_b, fused, N);

    const float* dinv_a = dinv;
    const float* dinv_t = dinv + N;
    const int*   row_a  = rowptr;
    const int*   row_t  = rowptr + N;

    // ---- spatial branch ----
    mfma_matmul<96><<<mmBlocks, 256, 0, stream>>>(fused, g1_W, lin, N);
    gather_kernel<<<nodeBlocks, 256, 0, stream>>>(row_a, edges, dinv_a, lin, g1_b, alpha, 0, h1, hacc, N);
    mfma_matmul<64><<<mmBlocks, 256, 0, stream>>>(h1, g2_W, lin, N);
    gather_kernel<<<nodeBlocks, 256, 0, stream>>>(row_a, edges, dinv_a, lin, g2_b, alpha, 1, h1, hacc, N);

    // ---- transit branch ----
    mfma_matmul<96><<<mmBlocks, 256, 0, stream>>>(fused, t1_W, lin, N);
    gather_kernel<<<nodeBlocks, 256, 0, stream>>>(row_t, edges, dinv_t, lin, t1_b, alpha, 0, h1, hacc, N);
    mfma_matmul<64><<<mmBlocks, 256, 0, stream>>>(h1, t2_W, lin, N);
    gather_kernel<<<nodeBlocks, 256, 0, stream>>>(row_t, edges, dinv_t, lin, t2_b, alpha, 2, h1, hacc, N);

    // ---- head ----
    head_kernel<<<headBlocks, 256, 0, stream>>>(hacc, fused, h_W1, h_b1, h_g, h_be,
                                                h_W2, h_b2, out, N);
}

// Round 7
// 762.630 us; speedup vs baseline: 1.2449x; 1.0800x over previous
//
#include <hip/hip_runtime.h>
#include <math.h>

// UrbanModelV2: encoder MLPs -> 4x GCNConv (2 graphs) -> gated combine -> LN-MLP head.
// N=100000, CTX=128, TGT=32, H=64, FUS=96, E1=1.6M, E2=0.8M. fp32 in/out.
//
// R7: fill_kernel was HBM-write-amplification bound (155MB HBM writes for 19MB
// of scattered int2 records). Fixes:
//  - edge record shrunk to 4B (src only): lin is pre-scaled by dinv at the MFMA
//    epilogue, so gather needs no per-edge dinv (pure sum, 1 shfl/edge).
//  - atomic-free fill: degcount keeps atomicAdd's return as the edge's rank;
//    fill stores srcs[rowptr[dst]+rank] with no cursor atomics.
//  - dinv computation fused into scan3; cursor buffer deleted.

#define LN_EPS 1e-5f

typedef __attribute__((ext_vector_type(8))) short short8;    // 8 bf16 = 4 VGPRs
typedef __attribute__((ext_vector_type(4))) float float4v;   // MFMA acc

__device__ __forceinline__ float gelu_exact(float x) {
    return 0.5f * x * (1.0f + erff(x * 0.70710678118654752440f));
}

__device__ __forceinline__ float wave_sum64(float v) {
#pragma unroll
    for (int off = 32; off > 0; off >>= 1)
        v += __shfl_xor(v, off, 64);
    return v;
}

__device__ __forceinline__ int load_edge(const void* ei, int is32, long idx) {
    return is32 ? ((const int*)ei)[idx] : (int)((const long long*)ei)[idx];
}

__device__ __forceinline__ unsigned short f32_to_bf16(float f) {
    unsigned int x = __float_as_uint(f);
    x += 0x7fffu + ((x >> 16) & 1u);   // RNE, finite values
    return (unsigned short)(x >> 16);
}
__device__ __forceinline__ float bf16_to_f32(unsigned short u) {
    return __uint_as_float((unsigned int)u << 16);
}

// ---------------- dtype detection ----------------
__global__ __launch_bounds__(256) void detect_kernel(const unsigned char* __restrict__ mask_bytes,
                                                     const int* __restrict__ ei_words,
                                                     int* __restrict__ flags) {
    __shared__ int f0, f1;
    if (threadIdx.x == 0) { f0 = 0; f1 = 0; }
    __syncthreads();
    int i = threadIdx.x;
    if ((i & 3) != 0 && mask_bytes[i] != 0) f0 = 1;
    if (i < 64 && ei_words[2 * i + 1] != 0) f1 = 1;
    __syncthreads();
    if (threadIdx.x == 0) { flags[0] = f0; flags[1] = f1; }
}

// ---------------- CSR build (both graphs; transit offset by N) ----------------
// degcount also records each edge's rank within its dst bucket (atomic return).
__global__ __launch_bounds__(256) void degcount_kernel(
    const void* __restrict__ ei1, int e1, const void* __restrict__ ei2, int e2,
    int n, const int* __restrict__ flags, int* __restrict__ deg,
    int* __restrict__ rank)
{
    int i = blockIdx.x * 256 + threadIdx.x;
    if (i >= e1 + e2) return;
    int is32 = flags[1];
    int d, off;
    if (i < e1) { d = load_edge(ei1, is32, (long)e1 + i); off = 0; }
    else        { int k = i - e1; d = load_edge(ei2, is32, (long)e2 + k); off = n; }
    rank[i] = atomicAdd(&deg[off + d], 1);
}

__global__ __launch_bounds__(256) void scan1_kernel(const int* __restrict__ deg, int n2,
                                                    int* __restrict__ bsum) {
    __shared__ int red[4];
    int i = blockIdx.x * 256 + threadIdx.x;
    int v = (i < n2) ? deg[i] : 0;
#pragma unroll
    for (int off = 32; off > 0; off >>= 1)
        v += __shfl_xor(v, off, 64);
    if ((threadIdx.x & 63) == 0) red[threadIdx.x >> 6] = v;
    __syncthreads();
    if (threadIdx.x == 0) bsum[blockIdx.x] = red[0] + red[1] + red[2] + red[3];
}

__global__ __launch_bounds__(1024) void scan2_kernel(int* __restrict__ bsum, int nb) {
    __shared__ int s[1024];
    int t = threadIdx.x;
    s[t] = (t < nb) ? bsum[t] : 0;
    __syncthreads();
    for (int off = 1; off < 1024; off <<= 1) {
        int v = (t >= off) ? s[t - off] : 0;
        __syncthreads();
        if (t >= off) s[t] += v;
        __syncthreads();
    }
    if (t < nb) bsum[t] = (t == 0) ? 0 : s[t - 1];
}

// rowptr + dinv from deg (dinv fused here: reads deg anyway)
__global__ __launch_bounds__(256) void scan3_kernel(const int* __restrict__ deg, int n2,
                                                    const int* __restrict__ boff,
                                                    int* __restrict__ rowptr,
                                                    float* __restrict__ dinv) {
    __shared__ int s[256];
    int t = threadIdx.x;
    int i = blockIdx.x * 256 + t;
    int v = (i < n2) ? deg[i] : 0;
    s[t] = v;
    __syncthreads();
    for (int off = 1; off < 256; off <<= 1) {
        int u = (t >= off) ? s[t - off] : 0;
        __syncthreads();
        if (t >= off) s[t] += u;
        __syncthreads();
    }
    int base = boff[blockIdx.x];
    if (i < n2) {
        rowptr[i] = base + s[t] - v;
        dinv[i] = rsqrtf((float)v + 1.0f);
        if (i == n2 - 1) rowptr[n2] = base + s[t];
    }
}

// atomic-free fill: pos = rowptr[dst] + rank[i]
__global__ __launch_bounds__(256) void fill_kernel(
    const void* __restrict__ ei1, int e1, const void* __restrict__ ei2, int e2,
    int n, const int* __restrict__ flags, const int* __restrict__ rowptr,
    const int* __restrict__ rank, int* __restrict__ srcs)
{
    int i = blockIdx.x * 256 + threadIdx.x;
    if (i >= e1 + e2) return;
    int is32 = flags[1];
    int s, d, off;
    if (i < e1) {
        s = load_edge(ei1, is32, i);
        d = load_edge(ei1, is32, (long)e1 + i);
        off = 0;
    } else {
        int k = i - e1;
        s = load_edge(ei2, is32, k);
        d = load_edge(ei2, is32, (long)e2 + k);
        off = n;
    }
    srcs[rowptr[off + d] + rank[i]] = s;
}

// ---------------- encoder -> fused bf16 [N,96], 8 rows/wave ----------------
__global__ __launch_bounds__(256) void encoder_kernel(
    const float* __restrict__ context, const float* __restrict__ target,
    const void* __restrict__ mask, const int* __restrict__ flags,
    const float* __restrict__ mask_token,
    const float* __restrict__ ce_W1, const float* __restrict__ ce_b1,
    const float* __restrict__ ce_g, const float* __restrict__ ce_beta,
    const float* __restrict__ ce_W2, const float* __restrict__ ce_b2,
    const float* __restrict__ te_W, const float* __restrict__ te_b,
    unsigned short* __restrict__ fused, int n)
{
    __shared__ float cbuf[32][64];
    __shared__ float tbuf[32][32];
    int w = threadIdx.x >> 6;
    int j = threadIdx.x & 63;
    int r0 = __builtin_amdgcn_readfirstlane(blockIdx.x * 32 + w * 8);
    if (r0 >= n) return;  // N % 32 == 0

    float y[8];
    float b1 = ce_b1[j];
#pragma unroll
    for (int r = 0; r < 8; ++r) y[r] = b1;
    const float* xr = context + (long)r0 * 128;
#pragma unroll 8
    for (int k = 0; k < 128; ++k) {
        float wv = ce_W1[k * 64 + j];
#pragma unroll
        for (int r = 0; r < 8; ++r)
            y[r] = fmaf(xr[r * 128 + k], wv, y[r]);
    }

    float lng = ce_g[j], lnb = ce_beta[j];
#pragma unroll
    for (int r = 0; r < 8; ++r) {
        float mean = wave_sum64(y[r]) * (1.0f / 64.0f);
        float xc = y[r] - mean;
        float var = wave_sum64(xc * xc) * (1.0f / 64.0f);
        cbuf[w * 8 + r][j] = gelu_exact(xc * rsqrtf(var + LN_EPS) * lng + lnb);
    }

    int tr = j >> 5;
    int tj = j & 31;
#pragma unroll
    for (int rr = 0; rr < 4; ++rr) {
        int r = tr + rr * 2;
        long mi = (long)(r0 + r) * 32 + tj;
        int mraw = flags[0] ? (int)((const unsigned char*)mask)[mi]
                            : ((const int*)mask)[mi];
        float m = mraw ? 1.0f : 0.0f;
        tbuf[w * 8 + r][tj] = target[mi] * (1.0f - m) + mask_token[tj] * m;
    }

    float y2[8];
    float b2 = ce_b2[j];
#pragma unroll
    for (int r = 0; r < 8; ++r) y2[r] = b2;
#pragma unroll 8
    for (int k = 0; k < 64; ++k) {
        float wv = ce_W2[k * 64 + j];
#pragma unroll
        for (int r = 0; r < 8; ++r)
            y2[r] = fmaf(cbuf[w * 8 + r][k], wv, y2[r]);
    }
#pragma unroll
    for (int r = 0; r < 8; ++r)
        fused[(long)(r0 + r) * 96 + j] = f32_to_bf16(gelu_exact(y2[r]));

#pragma unroll
    for (int rr = 0; rr < 4; ++rr) {
        int r = tr + rr * 2;
        float y3 = te_b[tj];
#pragma unroll
        for (int k = 0; k < 32; ++k)
            y3 = fmaf(tbuf[w * 8 + r][k], te_W[k * 32 + tj], y3);
        fused[(long)(r0 + r) * 96 + 64 + tj] = f32_to_bf16(gelu_exact(y3));
    }
}

// ---------------- MFMA matmul with row scale: y_bf16 = (x @ W) * scale[row] ----------------
// Wave computes 16x64 tiles (4 n-tiles of 16x16x32 MFMA). W -> LDS bf16
// transposed (stride K+8: 16B-aligned, 2-way alias free), B-frags in registers
// across grid-strided row loop. A: lane(m=lane&15,q=lane>>4) 16B load.
// C/D: col=lane&15, row=q*4+reg.
template <int K>
__global__ __launch_bounds__(256) void mfma_matmul(const unsigned short* __restrict__ x,
                                                   const float* __restrict__ W,
                                                   const float* __restrict__ scale,
                                                   unsigned short* __restrict__ y, int n) {
    constexpr int KS = K / 32;
    constexpr int STRIDE = K + 8;
    __shared__ __align__(16) unsigned short wt[64 * STRIDE];

    int n0 = threadIdx.x & 63;
    int kk = threadIdx.x >> 6;
    for (int k = kk; k < K; k += 4)
        wt[n0 * STRIDE + k] = f32_to_bf16(W[k * 64 + n0]);
    __syncthreads();

    int w = threadIdx.x >> 6;
    int lane = threadIdx.x & 63;
    int c = lane & 15;
    int q = lane >> 4;

    short8 bfrag[KS][4];
#pragma unroll
    for (int s = 0; s < KS; ++s)
#pragma unroll
        for (int nt = 0; nt < 4; ++nt)
            bfrag[s][nt] = *(const short8*)&wt[(nt * 16 + c) * STRIDE + s * 32 + q * 8];

    int T = n >> 4;
    int stride = gridDim.x * 4;
    for (int t = __builtin_amdgcn_readfirstlane(blockIdx.x * 4 + w); t < T; t += stride) {
        int r0 = t << 4;
        const unsigned short* xa = x + (size_t)(r0 + c) * K + q * 8;
        float4v acc[4] = {{0,0,0,0},{0,0,0,0},{0,0,0,0},{0,0,0,0}};
#pragma unroll
        for (int s = 0; s < KS; ++s) {
            short8 a = *(const short8*)(xa + s * 32);
#pragma unroll
            for (int nt = 0; nt < 4; ++nt)
                acc[nt] = __builtin_amdgcn_mfma_f32_16x16x32_bf16(a, bfrag[s][nt], acc[nt], 0, 0, 0);
        }
        float sc[4];
#pragma unroll
        for (int reg = 0; reg < 4; ++reg)
            sc[reg] = scale[r0 + q * 4 + reg];
#pragma unroll
        for (int nt = 0; nt < 4; ++nt)
#pragma unroll
            for (int reg = 0; reg < 4; ++reg)
                y[(size_t)(r0 + q * 4 + reg) * 64 + nt * 16 + c] = f32_to_bf16(acc[nt][reg] * sc[reg]);
    }
}

// ---------------- gather + fused finalize (wave/node; lin pre-scaled by dinv) ----------------
// pre = dinv_d * (sum_edges lin'[src] + lin'[node]) + b   (lin' = dinv .* (x@W))
// mode 0: outb = bf16(gelu(pre)); mode 1: outf = a*pre; mode 2: outf += (1-a)*pre
__global__ __launch_bounds__(256) void gather_kernel(
    const int* __restrict__ rowptr, const int* __restrict__ srcs,
    const float* __restrict__ dinv, const unsigned short* __restrict__ lin,
    const float* __restrict__ b, const float* __restrict__ alpha_ptr, int mode,
    unsigned short* __restrict__ outb, float* __restrict__ outf, int n)
{
    int w = threadIdx.x >> 6;
    int j = threadIdx.x & 63;
    int node = __builtin_amdgcn_readfirstlane(blockIdx.x * 4 + w);
    if (node >= n) return;

    int beg = rowptr[node];
    int end = rowptr[node + 1];
    float acc = 0.0f;
    for (int base = beg; base < end; base += 64) {
        int cnt = end - base;
        if (cnt > 64) cnt = 64;
        int sj = (j < cnt) ? srcs[base + j] : 0;
        int t = 0;
        for (; t + 4 <= cnt; t += 4) {
            int s0 = __shfl(sj, t, 64),     s1 = __shfl(sj, t + 1, 64);
            int s2 = __shfl(sj, t + 2, 64), s3 = __shfl(sj, t + 3, 64);
            float v0 = bf16_to_f32(lin[(long)s0 * 64 + j]);
            float v1 = bf16_to_f32(lin[(long)s1 * 64 + j]);
            float v2 = bf16_to_f32(lin[(long)s2 * 64 + j]);
            float v3 = bf16_to_f32(lin[(long)s3 * 64 + j]);
            acc += (v0 + v1) + (v2 + v3);
        }
        for (; t < cnt; ++t) {
            int s = __shfl(sj, t, 64);
            acc += bf16_to_f32(lin[(long)s * 64 + j]);
        }
    }
    float dd = dinv[node];
    float pre = fmaf(dd, acc + bf16_to_f32(lin[(long)node * 64 + j]), b[j]);

    long oi = (long)node * 64 + j;
    if (mode == 0) {
        outb[oi] = f32_to_bf16(gelu_exact(pre));
    } else {
        float a = 1.0f / (1.0f + expf(-alpha_ptr[0]));
        if (mode == 1) outf[oi] = a * pre;
        else           outf[oi] += (1.0f - a) * pre;
    }
}

// ---------------- head: 4 rows/wave, stage-1 via wave-uniform scalar loads ----------------
__global__ __launch_bounds__(256) void head_kernel(
    const float* __restrict__ hacc, const unsigned short* __restrict__ fused,
    const float* __restrict__ h_W1, const float* __restrict__ h_b1,
    const float* __restrict__ h_g, const float* __restrict__ h_beta,
    const float* __restrict__ h_W2, const float* __restrict__ h_b2,
    float* __restrict__ out, int n)
{
    __shared__ float z2[16][64];
    int w = threadIdx.x >> 6;
    int j = threadIdx.x & 63;
    int r0 = __builtin_amdgcn_readfirstlane(blockIdx.x * 16 + w * 4);
    if (r0 >= n) return;  // N % 16 == 0

    const float* hr = hacc + (size_t)r0 * 64;
    const unsigned short* fr = fused + (size_t)r0 * 96;

    float y[4];
    float b1 = h_b1[j];
#pragma unroll
    for (int r = 0; r < 4; ++r) y[r] = b1;
#pragma unroll 8
    for (int k = 0; k < 64; ++k) {
        float wv = h_W1[k * 64 + j];
#pragma unroll
        for (int r = 0; r < 4; ++r)
            y[r] = fmaf(hr[r * 64 + k], wv, y[r]);
    }
#pragma unroll 8
    for (int k = 0; k < 96; ++k) {
        float wv = h_W1[(64 + k) * 64 + j];
#pragma unroll
        for (int r = 0; r < 4; ++r)
            y[r] = fmaf(bf16_to_f32(fr[r * 96 + k]), wv, y[r]);
    }

    float lng = h_g[j], lnb = h_beta[j];
#pragma unroll
    for (int r = 0; r < 4; ++r) {
        float mean = wave_sum64(y[r]) * (1.0f / 64.0f);
        float xc = y[r] - mean;
        float var = wave_sum64(xc * xc) * (1.0f / 64.0f);
        z2[w * 4 + r][j] = gelu_exact(xc * rsqrtf(var + LN_EPS) * lng + lnb);
    }

    int tr = j >> 5;
    int tj = j & 31;
#pragma unroll
    for (int rr = 0; rr < 2; ++rr) {
        int r = tr + rr * 2;
        float o = h_b2[tj];
#pragma unroll
        for (int k = 0; k < 64; ++k)
            o = fmaf(z2[w * 4 + r][k], h_W2[k * 32 + tj], o);
        out[(long)(r0 + r) * 32 + tj] = o;
    }
}

extern "C" void kernel_launch(void* const* d_in, const int* in_sizes, int n_in,
                              void* d_out, int out_size, void* d_ws, size_t ws_size,
                              hipStream_t stream) {
    const float* context    = (const float*)d_in[0];
    const float* target     = (const float*)d_in[1];
    const void*  mask       = d_in[2];
    const void*  adj_ei     = d_in[3];
    const void*  tr_ei      = d_in[4];
    const float* mask_token = (const float*)d_in[5];
    const float* ce_W1 = (const float*)d_in[6];
    const float* ce_b1 = (const float*)d_in[7];
    const float* ce_g  = (const float*)d_in[8];
    const float* ce_be = (const float*)d_in[9];
    const float* ce_W2 = (const float*)d_in[10];
    const float* ce_b2 = (const float*)d_in[11];
    const float* te_W  = (const float*)d_in[12];
    const float* te_b  = (const float*)d_in[13];
    const float* g1_W  = (const float*)d_in[14];
    const float* g1_b  = (const float*)d_in[15];
    const float* g2_W  = (const float*)d_in[16];
    const float* g2_b  = (const float*)d_in[17];
    const float* t1_W  = (const float*)d_in[18];
    const float* t1_b  = (const float*)d_in[19];
    const float* t2_W  = (const float*)d_in[20];
    const float* t2_b  = (const float*)d_in[21];
    const float* alpha = (const float*)d_in[22];
    const float* h_W1  = (const float*)d_in[23];
    const float* h_b1  = (const float*)d_in[24];
    const float* h_g   = (const float*)d_in[25];
    const float* h_be  = (const float*)d_in[26];
    const float* h_W2  = (const float*)d_in[27];
    const float* h_b2  = (const float*)d_in[28];

    const int N  = in_sizes[0] / 128;
    const int E1 = in_sizes[3] / 2;
    const int E2 = in_sizes[4] / 2;
    const int E  = E1 + E2;
    const int N2 = 2 * N;
    const int nb = (N2 + 255) / 256;

    // ---- workspace layout ----
    char* p = (char*)d_ws;
    int*   flags  = (int*)p;                    p += 256;
    unsigned short* fused = (unsigned short*)p; p += (size_t)N * 96 * 2;
    unsigned short* lin   = (unsigned short*)p; p += (size_t)N * 64 * 2;
    unsigned short* h1    = (unsigned short*)p; p += (size_t)N * 64 * 2;
    float* hacc   = (float*)p;                  p += (size_t)N * 64 * 4;
    float* dinv   = (float*)p;                  p += (size_t)N2 * 4;
    int*   deg    = (int*)p;                    p += (size_t)N2 * 4;
    int*   rowptr = (int*)p;                    p += (size_t)(N2 + 64) * 4;
    int*   rank   = (int*)p;                    p += (size_t)E * 4;
    int*   bsum   = (int*)p;                    p += 1024 * 4;
    int*   srcs   = (int*)p;                    p += (size_t)E * 4;
    float* out    = (float*)d_out;

    const unsigned rowBlocks32 = (unsigned)((N + 31) / 32);
    const unsigned headBlocks  = (unsigned)((N + 15) / 16);
    const unsigned nodeBlocks  = (unsigned)((N + 3) / 4);
    const unsigned eBlocks     = (unsigned)((E + 255) / 256);
    const unsigned mmBlocks    = 391;

    detect_kernel<<<1, 256, 0, stream>>>((const unsigned char*)mask, (const int*)adj_ei, flags);
    hipMemsetAsync(deg, 0, (size_t)N2 * sizeof(int), stream);

    // ---- CSR build (both graphs) ----
    degcount_kernel<<<eBlocks, 256, 0, stream>>>(adj_ei, E1, tr_ei, E2, N, flags, deg, rank);
    scan1_kernel<<<nb, 256, 0, stream>>>(deg, N2, bsum);
    scan2_kernel<<<1, 1024, 0, stream>>>(bsum, nb);
    scan3_kernel<<<nb, 256, 0, stream>>>(deg, N2, bsum, rowptr, dinv);
    fill_kernel<<<eBlocks, 256, 0, stream>>>(adj_ei, E1, tr_ei, E2, N, flags, rowptr, rank, srcs);

    // ---- encoders -> fused (bf16) ----
    encoder_kernel<<<rowBlocks32, 256, 0, stream>>>(context, target, mask, flags, mask_token,
                                                    ce_W1, ce_b1, ce_g, ce_be, ce_W2, ce_b2,
                                                    te_W, te_b, fused, N);

    const float* dinv_a = dinv;
    const float* dinv_t = dinv + N;
    const int*   row_a  = rowptr;
    const int*   row_t  = rowptr + N;

    // ---- spatial branch ----
    mfma_matmul<96><<<mmBlocks, 256, 0, stream>>>(fused, g1_W, dinv_a, lin, N);
    gather_kernel<<<nodeBlocks, 256, 0, stream>>>(row_a, srcs, dinv_a, lin, g1_b, alpha, 0, h1, hacc, N);
    mfma_matmul<64><<<mmBlocks, 256, 0, stream>>>(h1, g2_W, dinv_a, lin, N);
    gather_kernel<<<nodeBlocks, 256, 0, stream>>>(row_a, srcs, dinv_a, lin, g2_b, alpha, 1, h1, hacc, N);

    // ---- transit branch ----
    mfma_matmul<96><<<mmBlocks, 256, 0, stream>>>(fused, t1_W, dinv_t, lin, N);
    gather_kernel<<<nodeBlocks, 256, 0, stream>>>(row_t, srcs, dinv_t, lin, t1_b, alpha, 0, h1, hacc, N);
    mfma_matmul<64><<<mmBlocks, 256, 0, stream>>>(h1, t2_W, dinv_t, lin, N);
    gather_kernel<<<nodeBlocks, 256, 0, stream>>>(row_t, srcs, dinv_t, lin, t2_b, alpha, 2, h1, hacc, N);

    // ---- head ----
    head_kernel<<<headBlocks, 256, 0, stream>>>(hacc, fused, h_W1, h_b1, h_g, h_be,
                                                h_W2, h_b2, out, N);
}

// Round 8
// 710.656 us; speedup vs baseline: 1.3360x; 1.0731x over previous
//
#include <hip/hip_runtime.h>
#include <math.h>

// UrbanModelV2: encoder MLPs -> 4x GCNConv (2 graphs) -> gated combine -> LN-MLP head.
// N=100000, CTX=128, TGT=32, H=64, FUS=96, E1=1.6M, E2=0.8M. fp32 in/out.
//
// R8: encoder (136us, VALU-bound at 33%) moved to MFMA:
//   prep (ctx->bf16 + target-encoder) -> mfma_ln (K=128, LN+GELU epilogue in
//   C-layout) -> mfma_gelu (K=64, -> fused[:,0:64], ostride 96).
// LN in C-layout: row q*4+reg spans 16 lanes x 4 ntile regs; two-pass mean/var
// via sum over nt + shfl_xor {1,2,4,8} (stays within the q-group).

#define LN_EPS 1e-5f

typedef __attribute__((ext_vector_type(8))) short short8;            // 8 bf16
typedef __attribute__((ext_vector_type(4))) float float4v;           // MFMA acc
typedef __attribute__((ext_vector_type(4))) unsigned short ushort4v; // 4 bf16

__device__ __forceinline__ float gelu_exact(float x) {
    return 0.5f * x * (1.0f + erff(x * 0.70710678118654752440f));
}

__device__ __forceinline__ float wave_sum64(float v) {
#pragma unroll
    for (int off = 32; off > 0; off >>= 1)
        v += __shfl_xor(v, off, 64);
    return v;
}

// reduce across the 16-lane quad-group (lane masks 1..8 stay within group)
__device__ __forceinline__ float qsum16(float v) {
#pragma unroll
    for (int m = 1; m < 16; m <<= 1)
        v += __shfl_xor(v, m, 64);
    return v;
}

__device__ __forceinline__ int load_edge(const void* ei, int is32, long idx) {
    return is32 ? ((const int*)ei)[idx] : (int)((const long long*)ei)[idx];
}

__device__ __forceinline__ unsigned short f32_to_bf16(float f) {
    unsigned int x = __float_as_uint(f);
    x += 0x7fffu + ((x >> 16) & 1u);   // RNE, finite values
    return (unsigned short)(x >> 16);
}
__device__ __forceinline__ float bf16_to_f32(unsigned short u) {
    return __uint_as_float((unsigned int)u << 16);
}

// ---------------- dtype detection ----------------
__global__ __launch_bounds__(256) void detect_kernel(const unsigned char* __restrict__ mask_bytes,
                                                     const int* __restrict__ ei_words,
                                                     int* __restrict__ flags) {
    __shared__ int f0, f1;
    if (threadIdx.x == 0) { f0 = 0; f1 = 0; }
    __syncthreads();
    int i = threadIdx.x;
    if ((i & 3) != 0 && mask_bytes[i] != 0) f0 = 1;
    if (i < 64 && ei_words[2 * i + 1] != 0) f1 = 1;
    __syncthreads();
    if (threadIdx.x == 0) { flags[0] = f0; flags[1] = f1; }
}

// ---------------- CSR build (both graphs; transit offset by N) ----------------
__global__ __launch_bounds__(256) void degcount_kernel(
    const void* __restrict__ ei1, int e1, const void* __restrict__ ei2, int e2,
    int n, const int* __restrict__ flags, int* __restrict__ deg,
    int* __restrict__ rank)
{
    int i = blockIdx.x * 256 + threadIdx.x;
    if (i >= e1 + e2) return;
    int is32 = flags[1];
    int d, off;
    if (i < e1) { d = load_edge(ei1, is32, (long)e1 + i); off = 0; }
    else        { int k = i - e1; d = load_edge(ei2, is32, (long)e2 + k); off = n; }
    rank[i] = atomicAdd(&deg[off + d], 1);
}

__global__ __launch_bounds__(256) void scan1_kernel(const int* __restrict__ deg, int n2,
                                                    int* __restrict__ bsum) {
    __shared__ int red[4];
    int i = blockIdx.x * 256 + threadIdx.x;
    int v = (i < n2) ? deg[i] : 0;
#pragma unroll
    for (int off = 32; off > 0; off >>= 1)
        v += __shfl_xor(v, off, 64);
    if ((threadIdx.x & 63) == 0) red[threadIdx.x >> 6] = v;
    __syncthreads();
    if (threadIdx.x == 0) bsum[blockIdx.x] = red[0] + red[1] + red[2] + red[3];
}

__global__ __launch_bounds__(1024) void scan2_kernel(int* __restrict__ bsum, int nb) {
    __shared__ int s[1024];
    int t = threadIdx.x;
    s[t] = (t < nb) ? bsum[t] : 0;
    __syncthreads();
    for (int off = 1; off < 1024; off <<= 1) {
        int v = (t >= off) ? s[t - off] : 0;
        __syncthreads();
        if (t >= off) s[t] += v;
        __syncthreads();
    }
    if (t < nb) bsum[t] = (t == 0) ? 0 : s[t - 1];
}

__global__ __launch_bounds__(256) void scan3_kernel(const int* __restrict__ deg, int n2,
                                                    const int* __restrict__ boff,
                                                    int* __restrict__ rowptr,
                                                    float* __restrict__ dinv) {
    __shared__ int s[256];
    int t = threadIdx.x;
    int i = blockIdx.x * 256 + t;
    int v = (i < n2) ? deg[i] : 0;
    s[t] = v;
    __syncthreads();
    for (int off = 1; off < 256; off <<= 1) {
        int u = (t >= off) ? s[t - off] : 0;
        __syncthreads();
        if (t >= off) s[t] += u;
        __syncthreads();
    }
    int base = boff[blockIdx.x];
    if (i < n2) {
        rowptr[i] = base + s[t] - v;
        dinv[i] = rsqrtf((float)v + 1.0f);
        if (i == n2 - 1) rowptr[n2] = base + s[t];
    }
}

__global__ __launch_bounds__(256) void fill_kernel(
    const void* __restrict__ ei1, int e1, const void* __restrict__ ei2, int e2,
    int n, const int* __restrict__ flags, const int* __restrict__ rowptr,
    const int* __restrict__ rank, int* __restrict__ srcs)
{
    int i = blockIdx.x * 256 + threadIdx.x;
    if (i >= e1 + e2) return;
    int is32 = flags[1];
    int s, d, off;
    if (i < e1) {
        s = load_edge(ei1, is32, i);
        d = load_edge(ei1, is32, (long)e1 + i);
        off = 0;
    } else {
        int k = i - e1;
        s = load_edge(ei2, is32, k);
        d = load_edge(ei2, is32, (long)e2 + k);
        off = n;
    }
    srcs[rowptr[off + d] + rank[i]] = s;
}

// ---------------- prep: ctx->bf16 + masked-target encoder -> fused[:,64:96] ----------------
__global__ __launch_bounds__(256) void prep_kernel(
    const float* __restrict__ context, const float* __restrict__ target,
    const void* __restrict__ mask, const int* __restrict__ flags,
    const float* __restrict__ mask_token,
    const float* __restrict__ te_W, const float* __restrict__ te_b,
    unsigned short* __restrict__ ctxb, unsigned short* __restrict__ fused, int n)
{
    __shared__ float tbuf[32][32];
    int w = threadIdx.x >> 6;
    int j = threadIdx.x & 63;
    int r0 = __builtin_amdgcn_readfirstlane(blockIdx.x * 32 + w * 8);
    if (r0 >= n) return;  // N % 32 == 0

    // context conversion: 8 rows x 128 = 1024 floats; 4 coalesced float4 passes
    const float4* src = (const float4*)(context + (size_t)r0 * 128);
    ushort4v* dst = (ushort4v*)(ctxb + (size_t)r0 * 128);
#pragma unroll
    for (int p = 0; p < 4; ++p) {
        float4 v = src[p * 64 + j];
        ushort4v o;
        o.x = f32_to_bf16(v.x); o.y = f32_to_bf16(v.y);
        o.z = f32_to_bf16(v.z); o.w = f32_to_bf16(v.w);
        dst[p * 64 + j] = o;
    }

    // masked target -> tbuf (wave-private)
    int tr = j >> 5;
    int tj = j & 31;
#pragma unroll
    for (int rr = 0; rr < 4; ++rr) {
        int r = tr + rr * 2;
        long mi = (long)(r0 + r) * 32 + tj;
        int mraw = flags[0] ? (int)((const unsigned char*)mask)[mi]
                            : ((const int*)mask)[mi];
        float m = mraw ? 1.0f : 0.0f;
        tbuf[w * 8 + r][tj] = target[mi] * (1.0f - m) + mask_token[tj] * m;
    }

    // target encoder (32 -> 32) -> fused[:,64:96]
#pragma unroll
    for (int rr = 0; rr < 4; ++rr) {
        int r = tr + rr * 2;
        float y3 = te_b[tj];
#pragma unroll
        for (int k = 0; k < 32; ++k)
            y3 = fmaf(tbuf[w * 8 + r][k], te_W[k * 32 + tj], y3);
        fused[(long)(r0 + r) * 96 + 64 + tj] = f32_to_bf16(gelu_exact(y3));
    }
}

// ---------------- MFMA encoder layer 1: LN+GELU epilogue ----------------
// y_bf16[N,64] = gelu(LN(ctx_bf16 @ W1 + b1) * g + beta)
__global__ __launch_bounds__(256) void mfma_ln_kernel(
    const unsigned short* __restrict__ x, const float* __restrict__ W,
    const float* __restrict__ bias, const float* __restrict__ g,
    const float* __restrict__ beta, unsigned short* __restrict__ y, int n)
{
    constexpr int K = 128, KS = K / 32, STRIDE = K + 8;
    __shared__ __align__(16) unsigned short wt[64 * STRIDE];
    int n0 = threadIdx.x & 63;
    int kk = threadIdx.x >> 6;
    for (int k = kk; k < K; k += 4)
        wt[n0 * STRIDE + k] = f32_to_bf16(W[k * 64 + n0]);
    __syncthreads();

    int w = threadIdx.x >> 6;
    int lane = threadIdx.x & 63;
    int c = lane & 15;
    int q = lane >> 4;

    short8 bfrag[KS][4];
#pragma unroll
    for (int s = 0; s < KS; ++s)
#pragma unroll
        for (int nt = 0; nt < 4; ++nt)
            bfrag[s][nt] = *(const short8*)&wt[(nt * 16 + c) * STRIDE + s * 32 + q * 8];

    float bs[4], gs[4], be[4];
#pragma unroll
    for (int nt = 0; nt < 4; ++nt) {
        bs[nt] = bias[nt * 16 + c];
        gs[nt] = g[nt * 16 + c];
        be[nt] = beta[nt * 16 + c];
    }

    int T = n >> 4;
    int stride = gridDim.x * 4;
    for (int t = __builtin_amdgcn_readfirstlane(blockIdx.x * 4 + w); t < T; t += stride) {
        int r0 = t << 4;
        const unsigned short* xa = x + (size_t)(r0 + c) * K + q * 8;
        float4v acc[4] = {{0,0,0,0},{0,0,0,0},{0,0,0,0},{0,0,0,0}};
#pragma unroll
        for (int s = 0; s < KS; ++s) {
            short8 a = *(const short8*)(xa + s * 32);
#pragma unroll
            for (int nt = 0; nt < 4; ++nt)
                acc[nt] = __builtin_amdgcn_mfma_f32_16x16x32_bf16(a, bfrag[s][nt], acc[nt], 0, 0, 0);
        }
        // epilogue: +bias, LN over the 64 cols of each row (q*4+reg), gelu
#pragma unroll
        for (int reg = 0; reg < 4; ++reg) {
            float v0 = acc[0][reg] + bs[0];
            float v1 = acc[1][reg] + bs[1];
            float v2 = acc[2][reg] + bs[2];
            float v3 = acc[3][reg] + bs[3];
            float mean = qsum16((v0 + v1) + (v2 + v3)) * (1.0f / 64.0f);
            float x0 = v0 - mean, x1 = v1 - mean, x2 = v2 - mean, x3 = v3 - mean;
            float var = qsum16((x0 * x0 + x1 * x1) + (x2 * x2 + x3 * x3)) * (1.0f / 64.0f);
            float rstd = rsqrtf(var + LN_EPS);
            size_t row = (size_t)(r0 + q * 4 + reg) * 64;
            y[row + 0 * 16 + c] = f32_to_bf16(gelu_exact(x0 * rstd * gs[0] + be[0]));
            y[row + 1 * 16 + c] = f32_to_bf16(gelu_exact(x1 * rstd * gs[1] + be[1]));
            y[row + 2 * 16 + c] = f32_to_bf16(gelu_exact(x2 * rstd * gs[2] + be[2]));
            y[row + 3 * 16 + c] = f32_to_bf16(gelu_exact(x3 * rstd * gs[3] + be[3]));
        }
    }
}

// ---------------- MFMA encoder layer 2: GELU epilogue, output stride 96 ----------------
__global__ __launch_bounds__(256) void mfma_gelu_kernel(
    const unsigned short* __restrict__ x, const float* __restrict__ W,
    const float* __restrict__ bias, unsigned short* __restrict__ y, int n)
{
    constexpr int K = 64, KS = K / 32, STRIDE = K + 8;
    __shared__ __align__(16) unsigned short wt[64 * STRIDE];
    int n0 = threadIdx.x & 63;
    int kk = threadIdx.x >> 6;
    for (int k = kk; k < K; k += 4)
        wt[n0 * STRIDE + k] = f32_to_bf16(W[k * 64 + n0]);
    __syncthreads();

    int w = threadIdx.x >> 6;
    int lane = threadIdx.x & 63;
    int c = lane & 15;
    int q = lane >> 4;

    short8 bfrag[KS][4];
#pragma unroll
    for (int s = 0; s < KS; ++s)
#pragma unroll
        for (int nt = 0; nt < 4; ++nt)
            bfrag[s][nt] = *(const short8*)&wt[(nt * 16 + c) * STRIDE + s * 32 + q * 8];

    float bs[4];
#pragma unroll
    for (int nt = 0; nt < 4; ++nt) bs[nt] = bias[nt * 16 + c];

    int T = n >> 4;
    int stride = gridDim.x * 4;
    for (int t = __builtin_amdgcn_readfirstlane(blockIdx.x * 4 + w); t < T; t += stride) {
        int r0 = t << 4;
        const unsigned short* xa = x + (size_t)(r0 + c) * K + q * 8;
        float4v acc[4] = {{0,0,0,0},{0,0,0,0},{0,0,0,0},{0,0,0,0}};
#pragma unroll
        for (int s = 0; s < KS; ++s) {
            short8 a = *(const short8*)(xa + s * 32);
#pragma unroll
            for (int nt = 0; nt < 4; ++nt)
                acc[nt] = __builtin_amdgcn_mfma_f32_16x16x32_bf16(a, bfrag[s][nt], acc[nt], 0, 0, 0);
        }
#pragma unroll
        for (int nt = 0; nt < 4; ++nt)
#pragma unroll
            for (int reg = 0; reg < 4; ++reg)
                y[(size_t)(r0 + q * 4 + reg) * 96 + nt * 16 + c] =
                    f32_to_bf16(gelu_exact(acc[nt][reg] + bs[nt]));
    }
}

// ---------------- MFMA GCN matmul: y_bf16 = (x @ W) * scale[row] ----------------
template <int K>
__global__ __launch_bounds__(256) void mfma_matmul(const unsigned short* __restrict__ x,
                                                   const float* __restrict__ W,
                                                   const float* __restrict__ scale,
                                                   unsigned short* __restrict__ y, int n) {
    constexpr int KS = K / 32;
    constexpr int STRIDE = K + 8;
    __shared__ __align__(16) unsigned short wt[64 * STRIDE];

    int n0 = threadIdx.x & 63;
    int kk = threadIdx.x >> 6;
    for (int k = kk; k < K; k += 4)
        wt[n0 * STRIDE + k] = f32_to_bf16(W[k * 64 + n0]);
    __syncthreads();

    int w = threadIdx.x >> 6;
    int lane = threadIdx.x & 63;
    int c = lane & 15;
    int q = lane >> 4;

    short8 bfrag[KS][4];
#pragma unroll
    for (int s = 0; s < KS; ++s)
#pragma unroll
        for (int nt = 0; nt < 4; ++nt)
            bfrag[s][nt] = *(const short8*)&wt[(nt * 16 + c) * STRIDE + s * 32 + q * 8];

    int T = n >> 4;
    int stride = gridDim.x * 4;
    for (int t = __builtin_amdgcn_readfirstlane(blockIdx.x * 4 + w); t < T; t += stride) {
        int r0 = t << 4;
        const unsigned short* xa = x + (size_t)(r0 + c) * K + q * 8;
        float4v acc[4] = {{0,0,0,0},{0,0,0,0},{0,0,0,0},{0,0,0,0}};
#pragma unroll
        for (int s = 0; s < KS; ++s) {
            short8 a = *(const short8*)(xa + s * 32);
#pragma unroll
            for (int nt = 0; nt < 4; ++nt)
                acc[nt] = __builtin_amdgcn_mfma_f32_16x16x32_bf16(a, bfrag[s][nt], acc[nt], 0, 0, 0);
        }
        float sc[4];
#pragma unroll
        for (int reg = 0; reg < 4; ++reg)
            sc[reg] = scale[r0 + q * 4 + reg];
#pragma unroll
        for (int nt = 0; nt < 4; ++nt)
#pragma unroll
            for (int reg = 0; reg < 4; ++reg)
                y[(size_t)(r0 + q * 4 + reg) * 64 + nt * 16 + c] = f32_to_bf16(acc[nt][reg] * sc[reg]);
    }
}

// ---------------- gather + fused finalize (wave/node; lin pre-scaled by dinv) ----------------
__global__ __launch_bounds__(256) void gather_kernel(
    const int* __restrict__ rowptr, const int* __restrict__ srcs,
    const float* __restrict__ dinv, const unsigned short* __restrict__ lin,
    const float* __restrict__ b, const float* __restrict__ alpha_ptr, int mode,
    unsigned short* __restrict__ outb, float* __restrict__ outf, int n)
{
    int w = threadIdx.x >> 6;
    int j = threadIdx.x & 63;
    int node = __builtin_amdgcn_readfirstlane(blockIdx.x * 4 + w);
    if (node >= n) return;

    int beg = rowptr[node];
    int end = rowptr[node + 1];
    float acc = 0.0f;
    for (int base = beg; base < end; base += 64) {
        int cnt = end - base;
        if (cnt > 64) cnt = 64;
        int sj = (j < cnt) ? srcs[base + j] : 0;
        int t = 0;
        for (; t + 8 <= cnt; t += 8) {
            float v[8];
#pragma unroll
            for (int u = 0; u < 8; ++u) {
                int s = __shfl(sj, t + u, 64);
                v[u] = bf16_to_f32(lin[(long)s * 64 + j]);
            }
            acc += ((v[0] + v[1]) + (v[2] + v[3])) + ((v[4] + v[5]) + (v[6] + v[7]));
        }
        for (; t < cnt; ++t) {
            int s = __shfl(sj, t, 64);
            acc += bf16_to_f32(lin[(long)s * 64 + j]);
        }
    }
    float dd = dinv[node];
    float pre = fmaf(dd, acc + bf16_to_f32(lin[(long)node * 64 + j]), b[j]);

    long oi = (long)node * 64 + j;
    if (mode == 0) {
        outb[oi] = f32_to_bf16(gelu_exact(pre));
    } else {
        float a = 1.0f / (1.0f + expf(-alpha_ptr[0]));
        if (mode == 1) outf[oi] = a * pre;
        else           outf[oi] += (1.0f - a) * pre;
    }
}

// ---------------- head: 4 rows/wave, stage-1 via wave-uniform scalar loads ----------------
__global__ __launch_bounds__(256) void head_kernel(
    const float* __restrict__ hacc, const unsigned short* __restrict__ fused,
    const float* __restrict__ h_W1, const float* __restrict__ h_b1,
    const float* __restrict__ h_g, const float* __restrict__ h_beta,
    const float* __restrict__ h_W2, const float* __restrict__ h_b2,
    float* __restrict__ out, int n)
{
    __shared__ float z2[16][64];
    int w = threadIdx.x >> 6;
    int j = threadIdx.x & 63;
    int r0 = __builtin_amdgcn_readfirstlane(blockIdx.x * 16 + w * 4);
    if (r0 >= n) return;  // N % 16 == 0

    const float* hr = hacc + (size_t)r0 * 64;
    const unsigned short* fr = fused + (size_t)r0 * 96;

    float y[4];
    float b1 = h_b1[j];
#pragma unroll
    for (int r = 0; r < 4; ++r) y[r] = b1;
#pragma unroll 8
    for (int k = 0; k < 64; ++k) {
        float wv = h_W1[k * 64 + j];
#pragma unroll
        for (int r = 0; r < 4; ++r)
            y[r] = fmaf(hr[r * 64 + k], wv, y[r]);
    }
#pragma unroll 8
    for (int k = 0; k < 96; ++k) {
        float wv = h_W1[(64 + k) * 64 + j];
#pragma unroll
        for (int r = 0; r < 4; ++r)
            y[r] = fmaf(bf16_to_f32(fr[r * 96 + k]), wv, y[r]);
    }

    float lng = h_g[j], lnb = h_beta[j];
#pragma unroll
    for (int r = 0; r < 4; ++r) {
        float mean = wave_sum64(y[r]) * (1.0f / 64.0f);
        float xc = y[r] - mean;
        float var = wave_sum64(xc * xc) * (1.0f / 64.0f);
        z2[w * 4 + r][j] = gelu_exact(xc * rsqrtf(var + LN_EPS) * lng + lnb);
    }

    int tr = j >> 5;
    int tj = j & 31;
#pragma unroll
    for (int rr = 0; rr < 2; ++rr) {
        int r = tr + rr * 2;
        float o = h_b2[tj];
#pragma unroll
        for (int k = 0; k < 64; ++k)
            o = fmaf(z2[w * 4 + r][k], h_W2[k * 32 + tj], o);
        out[(long)(r0 + r) * 32 + tj] = o;
    }
}

extern "C" void kernel_launch(void* const* d_in, const int* in_sizes, int n_in,
                              void* d_out, int out_size, void* d_ws, size_t ws_size,
                              hipStream_t stream) {
    const float* context    = (const float*)d_in[0];
    const float* target     = (const float*)d_in[1];
    const void*  mask       = d_in[2];
    const void*  adj_ei     = d_in[3];
    const void*  tr_ei      = d_in[4];
    const float* mask_token = (const float*)d_in[5];
    const float* ce_W1 = (const float*)d_in[6];
    const float* ce_b1 = (const float*)d_in[7];
    const float* ce_g  = (const float*)d_in[8];
    const float* ce_be = (const float*)d_in[9];
    const float* ce_W2 = (const float*)d_in[10];
    const float* ce_b2 = (const float*)d_in[11];
    const float* te_W  = (const float*)d_in[12];
    const float* te_b  = (const float*)d_in[13];
    const float* g1_W  = (const float*)d_in[14];
    const float* g1_b  = (const float*)d_in[15];
    const float* g2_W  = (const float*)d_in[16];
    const float* g2_b  = (const float*)d_in[17];
    const float* t1_W  = (const float*)d_in[18];
    const float* t1_b  = (const float*)d_in[19];
    const float* t2_W  = (const float*)d_in[20];
    const float* t2_b  = (const float*)d_in[21];
    const float* alpha = (const float*)d_in[22];
    const float* h_W1  = (const float*)d_in[23];
    const float* h_b1  = (const float*)d_in[24];
    const float* h_g   = (const float*)d_in[25];
    const float* h_be  = (const float*)d_in[26];
    const float* h_W2  = (const float*)d_in[27];
    const float* h_b2  = (const float*)d_in[28];

    const int N  = in_sizes[0] / 128;
    const int E1 = in_sizes[3] / 2;
    const int E2 = in_sizes[4] / 2;
    const int E  = E1 + E2;
    const int N2 = 2 * N;
    const int nb = (N2 + 255) / 256;

    // ---- workspace layout ----
    char* p = (char*)d_ws;
    int*   flags  = (int*)p;                    p += 256;
    unsigned short* ctxb  = (unsigned short*)p; p += (size_t)N * 128 * 2;
    unsigned short* fused = (unsigned short*)p; p += (size_t)N * 96 * 2;
    unsigned short* cb    = (unsigned short*)p; p += (size_t)N * 64 * 2;
    unsigned short* lin   = (unsigned short*)p; p += (size_t)N * 64 * 2;
    unsigned short* h1    = (unsigned short*)p; p += (size_t)N * 64 * 2;
    float* hacc   = (float*)p;                  p += (size_t)N * 64 * 4;
    float* dinv   = (float*)p;                  p += (size_t)N2 * 4;
    int*   deg    = (int*)p;                    p += (size_t)N2 * 4;
    int*   rowptr = (int*)p;                    p += (size_t)(N2 + 64) * 4;
    int*   rank   = (int*)p;                    p += (size_t)E * 4;
    int*   bsum   = (int*)p;                    p += 1024 * 4;
    int*   srcs   = (int*)p;                    p += (size_t)E * 4;
    float* out    = (float*)d_out;

    const unsigned rowBlocks32 = (unsigned)((N + 31) / 32);
    const unsigned headBlocks  = (unsigned)((N + 15) / 16);
    const unsigned nodeBlocks  = (unsigned)((N + 3) / 4);
    const unsigned eBlocks     = (unsigned)((E + 255) / 256);
    const unsigned mmBlocks    = 391;

    detect_kernel<<<1, 256, 0, stream>>>((const unsigned char*)mask, (const int*)adj_ei, flags);
    hipMemsetAsync(deg, 0, (size_t)N2 * sizeof(int), stream);

    // ---- CSR build (both graphs) ----
    degcount_kernel<<<eBlocks, 256, 0, stream>>>(adj_ei, E1, tr_ei, E2, N, flags, deg, rank);
    scan1_kernel<<<nb, 256, 0, stream>>>(deg, N2, bsum);
    scan2_kernel<<<1, 1024, 0, stream>>>(bsum, nb);
    scan3_kernel<<<nb, 256, 0, stream>>>(deg, N2, bsum, rowptr, dinv);
    fill_kernel<<<eBlocks, 256, 0, stream>>>(adj_ei, E1, tr_ei, E2, N, flags, rowptr, rank, srcs);

    // ---- encoder: prep -> MFMA layer1 (LN+GELU) -> MFMA layer2 (GELU) ----
    prep_kernel<<<rowBlocks32, 256, 0, stream>>>(context, target, mask, flags, mask_token,
                                                 te_W, te_b, ctxb, fused, N);
    mfma_ln_kernel<<<mmBlocks, 256, 0, stream>>>(ctxb, ce_W1, ce_b1, ce_g, ce_be, cb, N);
    mfma_gelu_kernel<<<mmBlocks, 256, 0, stream>>>(cb, ce_W2, ce_b2, fused, N);

    const float* dinv_a = dinv;
    const float* dinv_t = dinv + N;
    const int*   row_a  = rowptr;
    const int*   row_t  = rowptr + N;

    // ---- spatial branch ----
    mfma_matmul<96><<<mmBlocks, 256, 0, stream>>>(fused, g1_W, dinv_a, lin, N);
    gather_kernel<<<nodeBlocks, 256, 0, stream>>>(row_a, srcs, dinv_a, lin, g1_b, alpha, 0, h1, hacc, N);
    mfma_matmul<64><<<mmBlocks, 256, 0, stream>>>(h1, g2_W, dinv_a, lin, N);
    gather_kernel<<<nodeBlocks, 256, 0, stream>>>(row_a, srcs, dinv_a, lin, g2_b, alpha, 1, h1, hacc, N);

    // ---- transit branch ----
    mfma_matmul<96><<<mmBlocks, 256, 0, stream>>>(fused, t1_W, dinv_t, lin, N);
    gather_kernel<<<nodeBlocks, 256, 0, stream>>>(row_t, srcs, dinv_t, lin, t1_b, alpha, 0, h1, hacc, N);
    mfma_matmul<64><<<mmBlocks, 256, 0, stream>>>(h1, t2_W, dinv_t, lin, N);
    gather_kernel<<<nodeBlocks, 256, 0, stream>>>(row_t, srcs, dinv_t, lin, t2_b, alpha, 2, h1, hacc, N);

    // ---- head ----
    head_kernel<<<headBlocks, 256, 0, stream>>>(hacc, fused, h_W1, h_b1, h_g, h_be,
                                                h_W2, h_b2, out, N);
}

// Round 9
// 645.089 us; speedup vs baseline: 1.4717x; 1.1016x over previous
//
#include <hip/hip_runtime.h>
#include <math.h>

// UrbanModelV2: encoder MLPs -> 4x GCNConv (2 graphs) -> gated combine -> LN-MLP head.
// N=100000, CTX=128, TGT=32, H=64, FUS=96, E1=1.6M, E2=0.8M. fp32 in/out.
//
// R9: head (107us, VALU-bound 46%) -> fully fused MFMA:
//   gather mode-2 emits gated combine as bf16 (hb); head does
//   [hb|fused] @ W1 (K=160 MFMA, split A-stream) -> LN(C-layout) -> gelu ->
//   wave-private LDS roundtrip -> @ W2 (K=64 MFMA) -> +b2 -> fp32 out.

#define LN_EPS 1e-5f

typedef __attribute__((ext_vector_type(8))) short short8;            // 8 bf16
typedef __attribute__((ext_vector_type(4))) float float4v;           // MFMA acc
typedef __attribute__((ext_vector_type(4))) unsigned short ushort4v; // 4 bf16

__device__ __forceinline__ float gelu_exact(float x) {
    return 0.5f * x * (1.0f + erff(x * 0.70710678118654752440f));
}

// reduce across the 16-lane quad-group (lane masks 1..8 stay within group)
__device__ __forceinline__ float qsum16(float v) {
#pragma unroll
    for (int m = 1; m < 16; m <<= 1)
        v += __shfl_xor(v, m, 64);
    return v;
}

__device__ __forceinline__ int load_edge(const void* ei, int is32, long idx) {
    return is32 ? ((const int*)ei)[idx] : (int)((const long long*)ei)[idx];
}

__device__ __forceinline__ unsigned short f32_to_bf16(float f) {
    unsigned int x = __float_as_uint(f);
    x += 0x7fffu + ((x >> 16) & 1u);   // RNE, finite values
    return (unsigned short)(x >> 16);
}
__device__ __forceinline__ float bf16_to_f32(unsigned short u) {
    return __uint_as_float((unsigned int)u << 16);
}

// ---------------- dtype detection ----------------
__global__ __launch_bounds__(256) void detect_kernel(const unsigned char* __restrict__ mask_bytes,
                                                     const int* __restrict__ ei_words,
                                                     int* __restrict__ flags) {
    __shared__ int f0, f1;
    if (threadIdx.x == 0) { f0 = 0; f1 = 0; }
    __syncthreads();
    int i = threadIdx.x;
    if ((i & 3) != 0 && mask_bytes[i] != 0) f0 = 1;
    if (i < 64 && ei_words[2 * i + 1] != 0) f1 = 1;
    __syncthreads();
    if (threadIdx.x == 0) { flags[0] = f0; flags[1] = f1; }
}

// ---------------- CSR build (both graphs; transit offset by N) ----------------
__global__ __launch_bounds__(256) void degcount_kernel(
    const void* __restrict__ ei1, int e1, const void* __restrict__ ei2, int e2,
    int n, const int* __restrict__ flags, int* __restrict__ deg,
    int* __restrict__ rank)
{
    int i = blockIdx.x * 256 + threadIdx.x;
    if (i >= e1 + e2) return;
    int is32 = flags[1];
    int d, off;
    if (i < e1) { d = load_edge(ei1, is32, (long)e1 + i); off = 0; }
    else        { int k = i - e1; d = load_edge(ei2, is32, (long)e2 + k); off = n; }
    rank[i] = atomicAdd(&deg[off + d], 1);
}

__global__ __launch_bounds__(256) void scan1_kernel(const int* __restrict__ deg, int n2,
                                                    int* __restrict__ bsum) {
    __shared__ int red[4];
    int i = blockIdx.x * 256 + threadIdx.x;
    int v = (i < n2) ? deg[i] : 0;
#pragma unroll
    for (int off = 32; off > 0; off >>= 1)
        v += __shfl_xor(v, off, 64);
    if ((threadIdx.x & 63) == 0) red[threadIdx.x >> 6] = v;
    __syncthreads();
    if (threadIdx.x == 0) bsum[blockIdx.x] = red[0] + red[1] + red[2] + red[3];
}

__global__ __launch_bounds__(1024) void scan2_kernel(int* __restrict__ bsum, int nb) {
    __shared__ int s[1024];
    int t = threadIdx.x;
    s[t] = (t < nb) ? bsum[t] : 0;
    __syncthreads();
    for (int off = 1; off < 1024; off <<= 1) {
        int v = (t >= off) ? s[t - off] : 0;
        __syncthreads();
        if (t >= off) s[t] += v;
        __syncthreads();
    }
    if (t < nb) bsum[t] = (t == 0) ? 0 : s[t - 1];
}

__global__ __launch_bounds__(256) void scan3_kernel(const int* __restrict__ deg, int n2,
                                                    const int* __restrict__ boff,
                                                    int* __restrict__ rowptr,
                                                    float* __restrict__ dinv) {
    __shared__ int s[256];
    int t = threadIdx.x;
    int i = blockIdx.x * 256 + t;
    int v = (i < n2) ? deg[i] : 0;
    s[t] = v;
    __syncthreads();
    for (int off = 1; off < 256; off <<= 1) {
        int u = (t >= off) ? s[t - off] : 0;
        __syncthreads();
        if (t >= off) s[t] += u;
        __syncthreads();
    }
    int base = boff[blockIdx.x];
    if (i < n2) {
        rowptr[i] = base + s[t] - v;
        dinv[i] = rsqrtf((float)v + 1.0f);
        if (i == n2 - 1) rowptr[n2] = base + s[t];
    }
}

__global__ __launch_bounds__(256) void fill_kernel(
    const void* __restrict__ ei1, int e1, const void* __restrict__ ei2, int e2,
    int n, const int* __restrict__ flags, const int* __restrict__ rowptr,
    const int* __restrict__ rank, int* __restrict__ srcs)
{
    int i = blockIdx.x * 256 + threadIdx.x;
    if (i >= e1 + e2) return;
    int is32 = flags[1];
    int s, d, off;
    if (i < e1) {
        s = load_edge(ei1, is32, i);
        d = load_edge(ei1, is32, (long)e1 + i);
        off = 0;
    } else {
        int k = i - e1;
        s = load_edge(ei2, is32, k);
        d = load_edge(ei2, is32, (long)e2 + k);
        off = n;
    }
    srcs[rowptr[off + d] + rank[i]] = s;
}

// ---------------- prep: ctx->bf16 + masked-target encoder -> fused[:,64:96] ----------------
__global__ __launch_bounds__(256) void prep_kernel(
    const float* __restrict__ context, const float* __restrict__ target,
    const void* __restrict__ mask, const int* __restrict__ flags,
    const float* __restrict__ mask_token,
    const float* __restrict__ te_W, const float* __restrict__ te_b,
    unsigned short* __restrict__ ctxb, unsigned short* __restrict__ fused, int n)
{
    __shared__ float tbuf[32][32];
    int w = threadIdx.x >> 6;
    int j = threadIdx.x & 63;
    int r0 = __builtin_amdgcn_readfirstlane(blockIdx.x * 32 + w * 8);
    if (r0 >= n) return;  // N % 32 == 0

    const float4* src = (const float4*)(context + (size_t)r0 * 128);
    ushort4v* dst = (ushort4v*)(ctxb + (size_t)r0 * 128);
#pragma unroll
    for (int p = 0; p < 4; ++p) {
        float4 v = src[p * 64 + j];
        ushort4v o;
        o.x = f32_to_bf16(v.x); o.y = f32_to_bf16(v.y);
        o.z = f32_to_bf16(v.z); o.w = f32_to_bf16(v.w);
        dst[p * 64 + j] = o;
    }

    int tr = j >> 5;
    int tj = j & 31;
#pragma unroll
    for (int rr = 0; rr < 4; ++rr) {
        int r = tr + rr * 2;
        long mi = (long)(r0 + r) * 32 + tj;
        int mraw = flags[0] ? (int)((const unsigned char*)mask)[mi]
                            : ((const int*)mask)[mi];
        float m = mraw ? 1.0f : 0.0f;
        tbuf[w * 8 + r][tj] = target[mi] * (1.0f - m) + mask_token[tj] * m;
    }

#pragma unroll
    for (int rr = 0; rr < 4; ++rr) {
        int r = tr + rr * 2;
        float y3 = te_b[tj];
#pragma unroll
        for (int k = 0; k < 32; ++k)
            y3 = fmaf(tbuf[w * 8 + r][k], te_W[k * 32 + tj], y3);
        fused[(long)(r0 + r) * 96 + 64 + tj] = f32_to_bf16(gelu_exact(y3));
    }
}

// ---------------- MFMA encoder layer 1: LN+GELU epilogue ----------------
__global__ __launch_bounds__(256) void mfma_ln_kernel(
    const unsigned short* __restrict__ x, const float* __restrict__ W,
    const float* __restrict__ bias, const float* __restrict__ g,
    const float* __restrict__ beta, unsigned short* __restrict__ y, int n)
{
    constexpr int K = 128, KS = K / 32, STRIDE = K + 8;
    __shared__ __align__(16) unsigned short wt[64 * STRIDE];
    int n0 = threadIdx.x & 63;
    int kk = threadIdx.x >> 6;
    for (int k = kk; k < K; k += 4)
        wt[n0 * STRIDE + k] = f32_to_bf16(W[k * 64 + n0]);
    __syncthreads();

    int w = threadIdx.x >> 6;
    int lane = threadIdx.x & 63;
    int c = lane & 15;
    int q = lane >> 4;

    short8 bfrag[KS][4];
#pragma unroll
    for (int s = 0; s < KS; ++s)
#pragma unroll
        for (int nt = 0; nt < 4; ++nt)
            bfrag[s][nt] = *(const short8*)&wt[(nt * 16 + c) * STRIDE + s * 32 + q * 8];

    float bs[4], gs[4], be[4];
#pragma unroll
    for (int nt = 0; nt < 4; ++nt) {
        bs[nt] = bias[nt * 16 + c];
        gs[nt] = g[nt * 16 + c];
        be[nt] = beta[nt * 16 + c];
    }

    int T = n >> 4;
    int stride = gridDim.x * 4;
    for (int t = __builtin_amdgcn_readfirstlane(blockIdx.x * 4 + w); t < T; t += stride) {
        int r0 = t << 4;
        const unsigned short* xa = x + (size_t)(r0 + c) * K + q * 8;
        float4v acc[4] = {{0,0,0,0},{0,0,0,0},{0,0,0,0},{0,0,0,0}};
#pragma unroll
        for (int s = 0; s < KS; ++s) {
            short8 a = *(const short8*)(xa + s * 32);
#pragma unroll
            for (int nt = 0; nt < 4; ++nt)
                acc[nt] = __builtin_amdgcn_mfma_f32_16x16x32_bf16(a, bfrag[s][nt], acc[nt], 0, 0, 0);
        }
#pragma unroll
        for (int reg = 0; reg < 4; ++reg) {
            float v0 = acc[0][reg] + bs[0];
            float v1 = acc[1][reg] + bs[1];
            float v2 = acc[2][reg] + bs[2];
            float v3 = acc[3][reg] + bs[3];
            float mean = qsum16((v0 + v1) + (v2 + v3)) * (1.0f / 64.0f);
            float x0 = v0 - mean, x1 = v1 - mean, x2 = v2 - mean, x3 = v3 - mean;
            float var = qsum16((x0 * x0 + x1 * x1) + (x2 * x2 + x3 * x3)) * (1.0f / 64.0f);
            float rstd = rsqrtf(var + LN_EPS);
            size_t row = (size_t)(r0 + q * 4 + reg) * 64;
            y[row + 0 * 16 + c] = f32_to_bf16(gelu_exact(x0 * rstd * gs[0] + be[0]));
            y[row + 1 * 16 + c] = f32_to_bf16(gelu_exact(x1 * rstd * gs[1] + be[1]));
            y[row + 2 * 16 + c] = f32_to_bf16(gelu_exact(x2 * rstd * gs[2] + be[2]));
            y[row + 3 * 16 + c] = f32_to_bf16(gelu_exact(x3 * rstd * gs[3] + be[3]));
        }
    }
}

// ---------------- MFMA encoder layer 2: GELU epilogue, output stride 96 ----------------
__global__ __launch_bounds__(256) void mfma_gelu_kernel(
    const unsigned short* __restrict__ x, const float* __restrict__ W,
    const float* __restrict__ bias, unsigned short* __restrict__ y, int n)
{
    constexpr int K = 64, KS = K / 32, STRIDE = K + 8;
    __shared__ __align__(16) unsigned short wt[64 * STRIDE];
    int n0 = threadIdx.x & 63;
    int kk = threadIdx.x >> 6;
    for (int k = kk; k < K; k += 4)
        wt[n0 * STRIDE + k] = f32_to_bf16(W[k * 64 + n0]);
    __syncthreads();

    int w = threadIdx.x >> 6;
    int lane = threadIdx.x & 63;
    int c = lane & 15;
    int q = lane >> 4;

    short8 bfrag[KS][4];
#pragma unroll
    for (int s = 0; s < KS; ++s)
#pragma unroll
        for (int nt = 0; nt < 4; ++nt)
            bfrag[s][nt] = *(const short8*)&wt[(nt * 16 + c) * STRIDE + s * 32 + q * 8];

    float bs[4];
#pragma unroll
    for (int nt = 0; nt < 4; ++nt) bs[nt] = bias[nt * 16 + c];

    int T = n >> 4;
    int stride = gridDim.x * 4;
    for (int t = __builtin_amdgcn_readfirstlane(blockIdx.x * 4 + w); t < T; t += stride) {
        int r0 = t << 4;
        const unsigned short* xa = x + (size_t)(r0 + c) * K + q * 8;
        float4v acc[4] = {{0,0,0,0},{0,0,0,0},{0,0,0,0},{0,0,0,0}};
#pragma unroll
        for (int s = 0; s < KS; ++s) {
            short8 a = *(const short8*)(xa + s * 32);
#pragma unroll
            for (int nt = 0; nt < 4; ++nt)
                acc[nt] = __builtin_amdgcn_mfma_f32_16x16x32_bf16(a, bfrag[s][nt], acc[nt], 0, 0, 0);
        }
#pragma unroll
        for (int nt = 0; nt < 4; ++nt)
#pragma unroll
            for (int reg = 0; reg < 4; ++reg)
                y[(size_t)(r0 + q * 4 + reg) * 96 + nt * 16 + c] =
                    f32_to_bf16(gelu_exact(acc[nt][reg] + bs[nt]));
    }
}

// ---------------- MFMA GCN matmul: y_bf16 = (x @ W) * scale[row] ----------------
template <int K>
__global__ __launch_bounds__(256) void mfma_matmul(const unsigned short* __restrict__ x,
                                                   const float* __restrict__ W,
                                                   const float* __restrict__ scale,
                                                   unsigned short* __restrict__ y, int n) {
    constexpr int KS = K / 32;
    constexpr int STRIDE = K + 8;
    __shared__ __align__(16) unsigned short wt[64 * STRIDE];

    int n0 = threadIdx.x & 63;
    int kk = threadIdx.x >> 6;
    for (int k = kk; k < K; k += 4)
        wt[n0 * STRIDE + k] = f32_to_bf16(W[k * 64 + n0]);
    __syncthreads();

    int w = threadIdx.x >> 6;
    int lane = threadIdx.x & 63;
    int c = lane & 15;
    int q = lane >> 4;

    short8 bfrag[KS][4];
#pragma unroll
    for (int s = 0; s < KS; ++s)
#pragma unroll
        for (int nt = 0; nt < 4; ++nt)
            bfrag[s][nt] = *(const short8*)&wt[(nt * 16 + c) * STRIDE + s * 32 + q * 8];

    int T = n >> 4;
    int stride = gridDim.x * 4;
    for (int t = __builtin_amdgcn_readfirstlane(blockIdx.x * 4 + w); t < T; t += stride) {
        int r0 = t << 4;
        const unsigned short* xa = x + (size_t)(r0 + c) * K + q * 8;
        float4v acc[4] = {{0,0,0,0},{0,0,0,0},{0,0,0,0},{0,0,0,0}};
#pragma unroll
        for (int s = 0; s < KS; ++s) {
            short8 a = *(const short8*)(xa + s * 32);
#pragma unroll
            for (int nt = 0; nt < 4; ++nt)
                acc[nt] = __builtin_amdgcn_mfma_f32_16x16x32_bf16(a, bfrag[s][nt], acc[nt], 0, 0, 0);
        }
        float sc[4];
#pragma unroll
        for (int reg = 0; reg < 4; ++reg)
            sc[reg] = scale[r0 + q * 4 + reg];
#pragma unroll
        for (int nt = 0; nt < 4; ++nt)
#pragma unroll
            for (int reg = 0; reg < 4; ++reg)
                y[(size_t)(r0 + q * 4 + reg) * 64 + nt * 16 + c] = f32_to_bf16(acc[nt][reg] * sc[reg]);
    }
}

// ---------------- gather + fused finalize (wave/node; lin pre-scaled by dinv) ----------------
// mode 0: outb = bf16(gelu(pre))
// mode 1: outf = a*pre                     (fp32 partial)
// mode 2: outb = bf16(outf + (1-a)*pre)    (gated combine -> bf16 for MFMA head)
__global__ __launch_bounds__(256) void gather_kernel(
    const int* __restrict__ rowptr, const int* __restrict__ srcs,
    const float* __restrict__ dinv, const unsigned short* __restrict__ lin,
    const float* __restrict__ b, const float* __restrict__ alpha_ptr, int mode,
    unsigned short* __restrict__ outb, float* __restrict__ outf, int n)
{
    int w = threadIdx.x >> 6;
    int j = threadIdx.x & 63;
    int node = __builtin_amdgcn_readfirstlane(blockIdx.x * 4 + w);
    if (node >= n) return;

    int beg = rowptr[node];
    int end = rowptr[node + 1];
    float acc = 0.0f;
    for (int base = beg; base < end; base += 64) {
        int cnt = end - base;
        if (cnt > 64) cnt = 64;
        int sj = (j < cnt) ? srcs[base + j] : 0;
        int t = 0;
        for (; t + 8 <= cnt; t += 8) {
            float v[8];
#pragma unroll
            for (int u = 0; u < 8; ++u) {
                int s = __shfl(sj, t + u, 64);
                v[u] = bf16_to_f32(lin[(long)s * 64 + j]);
            }
            acc += ((v[0] + v[1]) + (v[2] + v[3])) + ((v[4] + v[5]) + (v[6] + v[7]));
        }
        for (; t < cnt; ++t) {
            int s = __shfl(sj, t, 64);
            acc += bf16_to_f32(lin[(long)s * 64 + j]);
        }
    }
    float dd = dinv[node];
    float pre = fmaf(dd, acc + bf16_to_f32(lin[(long)node * 64 + j]), b[j]);

    long oi = (long)node * 64 + j;
    if (mode == 0) {
        outb[oi] = f32_to_bf16(gelu_exact(pre));
    } else {
        float a = 1.0f / (1.0f + expf(-alpha_ptr[0]));
        if (mode == 1) outf[oi] = a * pre;
        else           outb[oi] = f32_to_bf16(outf[oi] + (1.0f - a) * pre);
    }
}

// ---------------- MFMA head: [hb|fused] @ W1 -> LN -> gelu -> @ W2 + b2 ----------------
__global__ __launch_bounds__(256) void head_mfma_kernel(
    const unsigned short* __restrict__ hb, const unsigned short* __restrict__ fused,
    const float* __restrict__ h_W1, const float* __restrict__ h_b1,
    const float* __restrict__ h_g, const float* __restrict__ h_beta,
    const float* __restrict__ h_W2, const float* __restrict__ h_b2,
    float* __restrict__ out, int n)
{
    constexpr int ST1 = 168;  // 160 + 8
    constexpr int ST2 = 72;   // 64 + 8
    __shared__ __align__(16) unsigned short wt1[64 * ST1];     // 21504 B
    __shared__ __align__(16) unsigned short wt2[32 * ST2];     // 4608 B
    __shared__ __align__(16) unsigned short zl[4][16 * ST2];   // 9216 B

    int n0 = threadIdx.x & 63;
    int kk = threadIdx.x >> 6;
    for (int k = kk; k < 160; k += 4)
        wt1[n0 * ST1 + k] = f32_to_bf16(h_W1[k * 64 + n0]);
    if (n0 < 32)
        for (int k = kk; k < 64; k += 4)
            wt2[n0 * ST2 + k] = f32_to_bf16(h_W2[k * 32 + n0]);
    __syncthreads();

    int w = threadIdx.x >> 6;
    int lane = threadIdx.x & 63;
    int c = lane & 15;
    int q = lane >> 4;

    short8 b1f[5][4];
#pragma unroll
    for (int s = 0; s < 5; ++s)
#pragma unroll
        for (int nt = 0; nt < 4; ++nt)
            b1f[s][nt] = *(const short8*)&wt1[(nt * 16 + c) * ST1 + s * 32 + q * 8];
    short8 b2f[2][2];
#pragma unroll
    for (int s = 0; s < 2; ++s)
#pragma unroll
        for (int nt = 0; nt < 2; ++nt)
            b2f[s][nt] = *(const short8*)&wt2[(nt * 16 + c) * ST2 + s * 32 + q * 8];

    float bs[4], gs[4], be[4];
#pragma unroll
    for (int nt = 0; nt < 4; ++nt) {
        bs[nt] = h_b1[nt * 16 + c];
        gs[nt] = h_g[nt * 16 + c];
        be[nt] = h_beta[nt * 16 + c];
    }
    float b2s[2];
#pragma unroll
    for (int nt = 0; nt < 2; ++nt) b2s[nt] = h_b2[nt * 16 + c];

    unsigned short* zw = zl[w];
    int T = n >> 4;
    int stride = gridDim.x * 4;
    for (int t = __builtin_amdgcn_readfirstlane(blockIdx.x * 4 + w); t < T; t += stride) {
        int r0 = t << 4;
        // stage 1: K=160 (hb: k 0..63, fused: k 64..159)
        const unsigned short* xh = hb + (size_t)(r0 + c) * 64 + q * 8;
        const unsigned short* xf = fused + (size_t)(r0 + c) * 96 + q * 8;
        float4v acc[4] = {{0,0,0,0},{0,0,0,0},{0,0,0,0},{0,0,0,0}};
#pragma unroll
        for (int s = 0; s < 2; ++s) {
            short8 a = *(const short8*)(xh + s * 32);
#pragma unroll
            for (int nt = 0; nt < 4; ++nt)
                acc[nt] = __builtin_amdgcn_mfma_f32_16x16x32_bf16(a, b1f[s][nt], acc[nt], 0, 0, 0);
        }
#pragma unroll
        for (int s = 0; s < 3; ++s) {
            short8 a = *(const short8*)(xf + s * 32);
#pragma unroll
            for (int nt = 0; nt < 4; ++nt)
                acc[nt] = __builtin_amdgcn_mfma_f32_16x16x32_bf16(a, b1f[2 + s][nt], acc[nt], 0, 0, 0);
        }
        // epilogue: +b1, LN per row (q*4+reg), gelu -> zl (wave-private)
#pragma unroll
        for (int reg = 0; reg < 4; ++reg) {
            float v0 = acc[0][reg] + bs[0];
            float v1 = acc[1][reg] + bs[1];
            float v2 = acc[2][reg] + bs[2];
            float v3 = acc[3][reg] + bs[3];
            float mean = qsum16((v0 + v1) + (v2 + v3)) * (1.0f / 64.0f);
            float x0 = v0 - mean, x1 = v1 - mean, x2 = v2 - mean, x3 = v3 - mean;
            float var = qsum16((x0 * x0 + x1 * x1) + (x2 * x2 + x3 * x3)) * (1.0f / 64.0f);
            float rstd = rsqrtf(var + LN_EPS);
            int row = q * 4 + reg;
            zw[row * ST2 + 0 * 16 + c] = f32_to_bf16(gelu_exact(x0 * rstd * gs[0] + be[0]));
            zw[row * ST2 + 1 * 16 + c] = f32_to_bf16(gelu_exact(x1 * rstd * gs[1] + be[1]));
            zw[row * ST2 + 2 * 16 + c] = f32_to_bf16(gelu_exact(x2 * rstd * gs[2] + be[2]));
            zw[row * ST2 + 3 * 16 + c] = f32_to_bf16(gelu_exact(x3 * rstd * gs[3] + be[3]));
        }
        // stage 2: z (16x64) @ W2 (64x32); same-wave LDS write->read, no barrier
        float4v acc2[2] = {{0,0,0,0},{0,0,0,0}};
#pragma unroll
        for (int s = 0; s < 2; ++s) {
            short8 a2 = *(const short8*)&zw[c * ST2 + s * 32 + q * 8];
#pragma unroll
            for (int nt = 0; nt < 2; ++nt)
                acc2[nt] = __builtin_amdgcn_mfma_f32_16x16x32_bf16(a2, b2f[s][nt], acc2[nt], 0, 0, 0);
        }
#pragma unroll
        for (int nt = 0; nt < 2; ++nt)
#pragma unroll
            for (int reg = 0; reg < 4; ++reg)
                out[(size_t)(r0 + q * 4 + reg) * 32 + nt * 16 + c] = acc2[nt][reg] + b2s[nt];
    }
}

extern "C" void kernel_launch(void* const* d_in, const int* in_sizes, int n_in,
                              void* d_out, int out_size, void* d_ws, size_t ws_size,
                              hipStream_t stream) {
    const float* context    = (const float*)d_in[0];
    const float* target     = (const float*)d_in[1];
    const void*  mask       = d_in[2];
    const void*  adj_ei     = d_in[3];
    const void*  tr_ei      = d_in[4];
    const float* mask_token = (const float*)d_in[5];
    const float* ce_W1 = (const float*)d_in[6];
    const float* ce_b1 = (const float*)d_in[7];
    const float* ce_g  = (const float*)d_in[8];
    const float* ce_be = (const float*)d_in[9];
    const float* ce_W2 = (const float*)d_in[10];
    const float* ce_b2 = (const float*)d_in[11];
    const float* te_W  = (const float*)d_in[12];
    const float* te_b  = (const float*)d_in[13];
    const float* g1_W  = (const float*)d_in[14];
    const float* g1_b  = (const float*)d_in[15];
    const float* g2_W  = (const float*)d_in[16];
    const float* g2_b  = (const float*)d_in[17];
    const float* t1_W  = (const float*)d_in[18];
    const float* t1_b  = (const float*)d_in[19];
    const float* t2_W  = (const float*)d_in[20];
    const float* t2_b  = (const float*)d_in[21];
    const float* alpha = (const float*)d_in[22];
    const float* h_W1  = (const float*)d_in[23];
    const float* h_b1  = (const float*)d_in[24];
    const float* h_g   = (const float*)d_in[25];
    const float* h_be  = (const float*)d_in[26];
    const float* h_W2  = (const float*)d_in[27];
    const float* h_b2  = (const float*)d_in[28];

    const int N  = in_sizes[0] / 128;
    const int E1 = in_sizes[3] / 2;
    const int E2 = in_sizes[4] / 2;
    const int E  = E1 + E2;
    const int N2 = 2 * N;
    const int nb = (N2 + 255) / 256;

    // ---- workspace layout ----
    char* p = (char*)d_ws;
    int*   flags  = (int*)p;                    p += 256;
    unsigned short* ctxb  = (unsigned short*)p; p += (size_t)N * 128 * 2;
    unsigned short* fused = (unsigned short*)p; p += (size_t)N * 96 * 2;
    unsigned short* cb    = (unsigned short*)p; p += (size_t)N * 64 * 2;
    unsigned short* lin   = (unsigned short*)p; p += (size_t)N * 64 * 2;
    unsigned short* h1    = (unsigned short*)p; p += (size_t)N * 64 * 2;
    unsigned short* hb    = (unsigned short*)p; p += (size_t)N * 64 * 2;
    float* hacc   = (float*)p;                  p += (size_t)N * 64 * 4;
    float* dinv   = (float*)p;                  p += (size_t)N2 * 4;
    int*   deg    = (int*)p;                    p += (size_t)N2 * 4;
    int*   rowptr = (int*)p;                    p += (size_t)(N2 + 64) * 4;
    int*   rank   = (int*)p;                    p += (size_t)E * 4;
    int*   bsum   = (int*)p;                    p += 1024 * 4;
    int*   srcs   = (int*)p;                    p += (size_t)E * 4;
    float* out    = (float*)d_out;

    const unsigned rowBlocks32 = (unsigned)((N + 31) / 32);
    const unsigned nodeBlocks  = (unsigned)((N + 3) / 4);
    const unsigned eBlocks     = (unsigned)((E + 255) / 256);
    const unsigned mmBlocks    = 391;

    detect_kernel<<<1, 256, 0, stream>>>((const unsigned char*)mask, (const int*)adj_ei, flags);
    hipMemsetAsync(deg, 0, (size_t)N2 * sizeof(int), stream);

    // ---- CSR build (both graphs) ----
    degcount_kernel<<<eBlocks, 256, 0, stream>>>(adj_ei, E1, tr_ei, E2, N, flags, deg, rank);
    scan1_kernel<<<nb, 256, 0, stream>>>(deg, N2, bsum);
    scan2_kernel<<<1, 1024, 0, stream>>>(bsum, nb);
    scan3_kernel<<<nb, 256, 0, stream>>>(deg, N2, bsum, rowptr, dinv);
    fill_kernel<<<eBlocks, 256, 0, stream>>>(adj_ei, E1, tr_ei, E2, N, flags, rowptr, rank, srcs);

    // ---- encoder ----
    prep_kernel<<<rowBlocks32, 256, 0, stream>>>(context, target, mask, flags, mask_token,
                                                 te_W, te_b, ctxb, fused, N);
    mfma_ln_kernel<<<mmBlocks, 256, 0, stream>>>(ctxb, ce_W1, ce_b1, ce_g, ce_be, cb, N);
    mfma_gelu_kernel<<<mmBlocks, 256, 0, stream>>>(cb, ce_W2, ce_b2, fused, N);

    const float* dinv_a = dinv;
    const float* dinv_t = dinv + N;
    const int*   row_a  = rowptr;
    const int*   row_t  = rowptr + N;

    // ---- spatial branch ----
    mfma_matmul<96><<<mmBlocks, 256, 0, stream>>>(fused, g1_W, dinv_a, lin, N);
    gather_kernel<<<nodeBlocks, 256, 0, stream>>>(row_a, srcs, dinv_a, lin, g1_b, alpha, 0, h1, hacc, N);
    mfma_matmul<64><<<mmBlocks, 256, 0, stream>>>(h1, g2_W, dinv_a, lin, N);
    gather_kernel<<<nodeBlocks, 256, 0, stream>>>(row_a, srcs, dinv_a, lin, g2_b, alpha, 1, hb, hacc, N);

    // ---- transit branch ----
    mfma_matmul<96><<<mmBlocks, 256, 0, stream>>>(fused, t1_W, dinv_t, lin, N);
    gather_kernel<<<nodeBlocks, 256, 0, stream>>>(row_t, srcs, dinv_t, lin, t1_b, alpha, 0, h1, hacc, N);
    mfma_matmul<64><<<mmBlocks, 256, 0, stream>>>(h1, t2_W, dinv_t, lin, N);
    gather_kernel<<<nodeBlocks, 256, 0, stream>>>(row_t, srcs, dinv_t, lin, t2_b, alpha, 2, hb, hacc, N);

    // ---- head (MFMA) ----
    head_mfma_kernel<<<mmBlocks, 256, 0, stream>>>(hb, fused, h_W1, h_b1, h_g, h_be,
                                                   h_W2, h_b2, out, N);
}